// Round 3
// baseline (2709.149 us; speedup 1.0000x reference)
//
#include <hip/hip_runtime.h>
#include <hip/hip_bf16.h>

typedef __hip_bfloat16 bf16;

#define B_SZ   2
#define T_SEQ  2048
#define C_DIM  1024
#define NH     16
#define NKV    4
#define HD     64

__device__ __forceinline__ float to_f(float x) { return x; }
__device__ __forceinline__ float to_f(bf16 x)  { return __bfloat162float(x); }

__device__ __forceinline__ void store_o(float* p, float v) { *p = v; }
__device__ __forceinline__ void store_o(bf16* p, float v)  { *p = __float2bfloat16(v); }

// ---------------------------------------------------------------------------
// Tiled GEMM: C[M,N] = A[M,K] @ W[K,N] + bias[N]; A fp32 or bf16, W/bias fp32,
// C fp32 or bf16. fp32 accumulate. 64x64 tile, BK=32, 256 thr, 4x4 micro-tile.
// ---------------------------------------------------------------------------
template <typename AT, typename CT>
__global__ __launch_bounds__(256) void gemm_bias_kernel(
    const AT* __restrict__ A, const float* __restrict__ W,
    const float* __restrict__ bias, CT* __restrict__ C,
    int M, int N, int K)
{
    const int BM = 64, BN = 64, BK = 32;
    __shared__ float As[BK][BM + 1];   // As[k][row]
    __shared__ float Ws[BK][BN + 1];   // Ws[k][col]

    int m0 = blockIdx.y * BM;
    int n0 = blockIdx.x * BN;
    int tid = threadIdx.x;
    int tx = tid & 15;
    int ty = tid >> 4;

    float acc[4][4] = {};

    for (int k0 = 0; k0 < K; k0 += BK) {
        for (int e = tid; e < BM * BK; e += 256) {
            int row = e >> 5;
            int kk  = e & 31;
            As[kk][row] = to_f(A[(size_t)(m0 + row) * K + k0 + kk]);
        }
        for (int e = tid; e < BK * BN; e += 256) {
            int kk = e >> 6;
            int n  = e & 63;
            Ws[kk][n] = W[(size_t)(k0 + kk) * N + n0 + n];
        }
        __syncthreads();

        #pragma unroll 8
        for (int kk = 0; kk < BK; ++kk) {
            float a[4], w[4];
            #pragma unroll
            for (int i = 0; i < 4; ++i) a[i] = As[kk][ty + 16 * i];
            #pragma unroll
            for (int j = 0; j < 4; ++j) w[j] = Ws[kk][tx + 16 * j];
            #pragma unroll
            for (int i = 0; i < 4; ++i)
                #pragma unroll
                for (int j = 0; j < 4; ++j)
                    acc[i][j] += a[i] * w[j];
        }
        __syncthreads();
    }

    #pragma unroll
    for (int i = 0; i < 4; ++i) {
        int row = m0 + ty + 16 * i;
        #pragma unroll
        for (int j = 0; j < 4; ++j) {
            int col = n0 + tx + 16 * j;
            store_o(&C[(size_t)row * N + col], acc[i][j] + bias[col]);
        }
    }
}

// ---------------------------------------------------------------------------
// RoPE (interleaved pairs), in-place on bf16 [B*T, n_heads*64] rows.
// ---------------------------------------------------------------------------
__global__ void rope_kernel(bf16* __restrict__ X, int n_heads, int total_pairs)
{
    int p = blockIdx.x * blockDim.x + threadIdx.x;
    if (p >= total_pairs) return;
    int i = p & 31;
    int r = p >> 5;
    int t = (r / n_heads) % T_SEQ;

    size_t base = (size_t)r * HD + 2 * i;
    float e = __bfloat162float(X[base]);
    float o = __bfloat162float(X[base + 1]);

    float freq = powf(10000.0f, -(float)(2 * i) / 64.0f);
    float ang  = (float)t * freq;
    float cs = cosf(ang);
    float sn = sinf(ang);

    X[base]     = __float2bfloat16(e * cs - o * sn);
    X[base + 1] = __float2bfloat16(e * sn + o * cs);
}

// ---------------------------------------------------------------------------
// Flash-style causal GQA attention. One wave per query row; 4 waves/block
// share LDS K/V chunks. Online softmax, fp32 state. bf16 in/out.
// ---------------------------------------------------------------------------
__global__ __launch_bounds__(256) void attn_kernel(
    const bf16* __restrict__ Q, const bf16* __restrict__ K,
    const bf16* __restrict__ V, bf16* __restrict__ O)
{
    __shared__ float sK[64][HD + 1];
    __shared__ float sV[64][HD + 1];
    __shared__ float sQ[4][HD];

    int wid  = threadIdx.x >> 6;
    int lane = threadIdx.x & 63;

    int rowblk = blockIdx.x;
    int t0 = (rowblk % (T_SEQ / 4)) * 4;
    int bh = rowblk / (T_SEQ / 4);
    int h  = bh % NH;
    int b  = bh / NH;
    int t  = t0 + wid;
    int kvh = h >> 2;

    const bf16* qrow = Q + (((size_t)b * T_SEQ + t) * NH + h) * HD;
    sQ[wid][lane] = __bfloat162float(qrow[lane]);

    const bf16* kbase = K + ((size_t)b * T_SEQ * NKV + kvh) * HD;
    const bf16* vbase = V + ((size_t)b * T_SEQ * NKV + kvh) * HD;

    float m = -INFINITY, s = 0.0f, o_acc = 0.0f;

    int nchunk = (t0 + 3) / 64 + 1;
    for (int c = 0; c < nchunk; ++c) {
        int j0 = c * 64;
        for (int e = threadIdx.x; e < 64 * HD; e += 256) {
            int j = e >> 6;
            int d = e & 63;
            size_t gidx = (size_t)(j0 + j) * NKV * HD + d;
            sK[j][d] = __bfloat162float(kbase[gidx]);
            sV[j][d] = __bfloat162float(vbase[gidx]);
        }
        __syncthreads();

        {
            float sc = 0.0f;
            const float* krow = &sK[lane][0];
            #pragma unroll 16
            for (int d = 0; d < HD; ++d) sc += sQ[wid][d] * krow[d];
            sc *= 0.125f;
            if (j0 + lane > t) sc = -INFINITY;

            float cm = sc;
            #pragma unroll
            for (int off = 32; off >= 1; off >>= 1)
                cm = fmaxf(cm, __shfl_xor(cm, off));
            float nm = fmaxf(m, cm);
            float alpha = __expf(m - nm);
            float p = __expf(sc - nm);

            float ps = p;
            #pragma unroll
            for (int off = 32; off >= 1; off >>= 1)
                ps += __shfl_xor(ps, off);
            s = s * alpha + ps;
            m = nm;

            float acc = 0.0f;
            #pragma unroll 16
            for (int jj = 0; jj < 64; ++jj) {
                float pj = __shfl(p, jj);
                acc += pj * sV[jj][lane];
            }
            o_acc = o_acc * alpha + acc;
        }
        __syncthreads();
    }

    float r = o_acc / s;
    O[(((size_t)b * T_SEQ + t) * NH + h) * HD + lane] = __float2bfloat16(r);
}

// ---------------------------------------------------------------------------
extern "C" void kernel_launch(void* const* d_in, const int* in_sizes, int n_in,
                              void* d_out, int out_size, void* d_ws, size_t ws_size,
                              hipStream_t stream)
{
    // Inputs fp32 (reference setup_inputs dtype); output fp32 (reference
    // output dtype). Intermediates bf16 in workspace.
    const float* x   = (const float*)d_in[0];
    const float* w_q = (const float*)d_in[1];
    const float* b_q = (const float*)d_in[2];
    const float* w_k = (const float*)d_in[3];
    const float* b_k = (const float*)d_in[4];
    const float* w_v = (const float*)d_in[5];
    const float* b_v = (const float*)d_in[6];
    const float* w_o = (const float*)d_in[7];
    const float* b_o = (const float*)d_in[8];
    float* out = (float*)d_out;

    char* ws = (char*)d_ws;
    bf16* Qb = (bf16*)(ws);                              // 8 MB
    bf16* Kb = (bf16*)(ws + ((size_t)8  << 20));         // 2 MB
    bf16* Vb = (bf16*)(ws + ((size_t)10 << 20));         // 2 MB
    bf16* Ab = (bf16*)(ws + ((size_t)12 << 20));         // 8 MB (total 20 MB)

    const int M = B_SZ * T_SEQ;   // 4096

    gemm_bias_kernel<float, bf16><<<dim3(C_DIM / 64, M / 64), 256, 0, stream>>>(
        x, w_q, b_q, Qb, M, C_DIM, C_DIM);
    gemm_bias_kernel<float, bf16><<<dim3((NKV * HD) / 64, M / 64), 256, 0, stream>>>(
        x, w_k, b_k, Kb, M, NKV * HD, C_DIM);
    gemm_bias_kernel<float, bf16><<<dim3((NKV * HD) / 64, M / 64), 256, 0, stream>>>(
        x, w_v, b_v, Vb, M, NKV * HD, C_DIM);

    {
        int pq = B_SZ * T_SEQ * NH * (HD / 2);
        rope_kernel<<<(pq + 255) / 256, 256, 0, stream>>>(Qb, NH, pq);
        int pk = B_SZ * T_SEQ * NKV * (HD / 2);
        rope_kernel<<<(pk + 255) / 256, 256, 0, stream>>>(Kb, NKV, pk);
    }

    attn_kernel<<<B_SZ * NH * T_SEQ / 4, 256, 0, stream>>>(Qb, Kb, Vb, Ab);

    gemm_bias_kernel<bf16, float><<<dim3(C_DIM / 64, M / 64), 256, 0, stream>>>(
        Ab, w_o, b_o, out, M, C_DIM, C_DIM);
}

// Round 4
// 1033.562 us; speedup vs baseline: 2.6212x; 2.6212x over previous
//
#include <hip/hip_runtime.h>
#include <hip/hip_bf16.h>

typedef __hip_bfloat16 bf16;
typedef __attribute__((ext_vector_type(8))) short short8_t;
typedef __attribute__((ext_vector_type(4))) float f32x4;

#define B_SZ   2
#define T_SEQ  2048
#define C_DIM  1024
#define NH     16
#define NKV    4
#define HD     64

__device__ __forceinline__ float to_f(float x) { return x; }
__device__ __forceinline__ float to_f(bf16 x)  { return __bfloat162float(x); }

__device__ __forceinline__ void store_o(float* p, float v) { *p = v; }
__device__ __forceinline__ void store_o(bf16* p, float v)  { *p = __float2bfloat16(v); }

// float -> bf16 bits (round-nearest-even), avoids struct-aliasing issues
__device__ __forceinline__ short f2bs(float f) {
    unsigned u = __float_as_uint(f);
    u += 0x7FFFu + ((u >> 16) & 1u);
    return (short)(u >> 16);
}

// ---------------------------------------------------------------------------
// Tiled GEMM: C[M,N] = A[M,K] @ W[K,N] + bias[N]; fp32 accumulate.
// 64x64 tile, BK=32, 256 thr, 4x4 micro-tile. (unchanged from round 3)
// ---------------------------------------------------------------------------
template <typename AT, typename CT>
__global__ __launch_bounds__(256) void gemm_bias_kernel(
    const AT* __restrict__ A, const float* __restrict__ W,
    const float* __restrict__ bias, CT* __restrict__ C,
    int M, int N, int K)
{
    const int BM = 64, BN = 64, BK = 32;
    __shared__ float As[BK][BM + 1];
    __shared__ float Ws[BK][BN + 1];

    int m0 = blockIdx.y * BM;
    int n0 = blockIdx.x * BN;
    int tid = threadIdx.x;
    int tx = tid & 15;
    int ty = tid >> 4;

    float acc[4][4] = {};

    for (int k0 = 0; k0 < K; k0 += BK) {
        for (int e = tid; e < BM * BK; e += 256) {
            int row = e >> 5;
            int kk  = e & 31;
            As[kk][row] = to_f(A[(size_t)(m0 + row) * K + k0 + kk]);
        }
        for (int e = tid; e < BK * BN; e += 256) {
            int kk = e >> 6;
            int n  = e & 63;
            Ws[kk][n] = W[(size_t)(k0 + kk) * N + n0 + n];
        }
        __syncthreads();

        #pragma unroll 8
        for (int kk = 0; kk < BK; ++kk) {
            float a[4], w[4];
            #pragma unroll
            for (int i = 0; i < 4; ++i) a[i] = As[kk][ty + 16 * i];
            #pragma unroll
            for (int j = 0; j < 4; ++j) w[j] = Ws[kk][tx + 16 * j];
            #pragma unroll
            for (int i = 0; i < 4; ++i)
                #pragma unroll
                for (int j = 0; j < 4; ++j)
                    acc[i][j] += a[i] * w[j];
        }
        __syncthreads();
    }

    #pragma unroll
    for (int i = 0; i < 4; ++i) {
        int row = m0 + ty + 16 * i;
        #pragma unroll
        for (int j = 0; j < 4; ++j) {
            int col = n0 + tx + 16 * j;
            store_o(&C[(size_t)row * N + col], acc[i][j] + bias[col]);
        }
    }
}

// ---------------------------------------------------------------------------
// RoPE (interleaved pairs), in-place on bf16 [B*T, n_heads*64] rows.
// ---------------------------------------------------------------------------
__global__ void rope_kernel(bf16* __restrict__ X, int n_heads, int total_pairs)
{
    int p = blockIdx.x * blockDim.x + threadIdx.x;
    if (p >= total_pairs) return;
    int i = p & 31;
    int r = p >> 5;
    int t = (r / n_heads) % T_SEQ;

    size_t base = (size_t)r * HD + 2 * i;
    float e = __bfloat162float(X[base]);
    float o = __bfloat162float(X[base + 1]);

    float freq = powf(10000.0f, -(float)(2 * i) / 64.0f);
    float ang  = (float)t * freq;
    float cs = cosf(ang);
    float sn = sinf(ang);

    X[base]     = __float2bfloat16(e * cs - o * sn);
    X[base + 1] = __float2bfloat16(e * sn + o * cs);
}

// ---------------------------------------------------------------------------
// MFMA flash attention. Block = 4 waves = 64 query rows of one (b,h).
// Wave w owns q rows [t0+16w, t0+16w+16). Iterate 64-key chunks:
//   QK^T via mfma_f32_16x16x32_bf16, online softmax in C-layout,
//   P->LDS (A-layout round trip), PV via MFMA with V^T staged in LDS.
// Layouts (verified, learn_hip m89/m91/m120):
//   A-frag: A[m=lane&15][k=quad*8+j]    B-frag: B[k=quad*8+j][n=lane&15]
//   C/D:    col=lane&15, row=quad*4+reg
// ---------------------------------------------------------------------------
__global__ __launch_bounds__(256) void attn_mfma_kernel(
    const short* __restrict__ Q, const short* __restrict__ K,
    const short* __restrict__ V, short* __restrict__ O)
{
    __shared__ short sK [64][72];     // [key][dim]  (+8 pad: 2-way banks = free)
    __shared__ short sVt[64][72];     // [dim][key]
    __shared__ short sP [4][16][72];  // per-wave P tile [q][key]

    const int tid  = threadIdx.x;
    const int w    = tid >> 6;
    const int lane = tid & 63;
    const int quad = lane >> 4;
    const int l16  = lane & 15;

    const int nT   = T_SEQ / 64;            // 32
    int blk  = blockIdx.x;
    int tblk = nT - 1 - (blk % nT);          // long blocks dispatched first
    int bh   = blk / nT;
    int h    = bh % NH;
    int b    = bh / NH;
    int t0   = tblk * 64;
    int kvh  = h >> 2;                       // repeat_interleave: kv head = h/4

    // Q fragments for this wave's 16 rows (held in registers all loop long)
    const short* qptr = Q + (((size_t)b * T_SEQ + t0 + 16 * w + l16) * NH + h) * HD;
    short8_t qf0 = *(const short8_t*)(qptr + quad * 8);
    short8_t qf1 = *(const short8_t*)(qptr + quad * 8 + 32);

    const short* kptr = K + ((size_t)b * T_SEQ * NKV + kvh) * HD;
    const short* vptr = V + ((size_t)b * T_SEQ * NKV + kvh) * HD;

    float mrow[4], lrow[4];
    f32x4 oacc[4];
    #pragma unroll
    for (int r = 0; r < 4; ++r) { mrow[r] = -INFINITY; lrow[r] = 0.0f; }
    #pragma unroll
    for (int dt = 0; dt < 4; ++dt) oacc[dt] = (f32x4){0.f, 0.f, 0.f, 0.f};

    for (int c = 0; c <= tblk; ++c) {
        int j0 = c * 64;

        // ---- stage K chunk: sK[key][dim], coalesced global, b128 LDS writes
        #pragma unroll
        for (int it = 0; it < 2; ++it) {
            int slot = tid + 256 * it;
            int key  = slot >> 3;
            int d0   = (slot & 7) * 8;
            *(short8_t*)&sK[key][d0] =
                *(const short8_t*)(kptr + (size_t)(j0 + key) * (NKV * HD) + d0);
        }
        // ---- stage V chunk transposed: sVt[dim][key]; lane-per-key mapping
        //      makes the 8 scalar LDS writes conflict-free (adjacent keys
        //      share a bank word -> 2-way = free).
        #pragma unroll
        for (int it = 0; it < 2; ++it) {
            int slot = tid + 256 * it;
            int key  = slot & 63;
            int d0   = (slot >> 6) * 8;
            short8_t v = *(const short8_t*)(vptr + (size_t)(j0 + key) * (NKV * HD) + d0);
            #pragma unroll
            for (int i = 0; i < 8; ++i) sVt[d0 + i][key] = v[i];
        }
        __syncthreads();

        // ---- S = Q K^T : 8 MFMAs -> S[16q][64key] in 4 accumulators
        f32x4 sacc[4];
        #pragma unroll
        for (int nt = 0; nt < 4; ++nt) sacc[nt] = (f32x4){0.f, 0.f, 0.f, 0.f};
        #pragma unroll
        for (int nt = 0; nt < 4; ++nt) {
            short8_t kf0 = *(const short8_t*)&sK[l16 + 16 * nt][0];
            short8_t kf1 = *(const short8_t*)&sK[l16 + 16 * nt][32];
            // note: fragment k-offset is quad*8 within each 32-wide half
            kf0 = *(const short8_t*)&sK[l16 + 16 * nt][quad * 8];
            kf1 = *(const short8_t*)&sK[l16 + 16 * nt][quad * 8 + 32];
            sacc[nt] = __builtin_amdgcn_mfma_f32_16x16x32_bf16(qf0, kf0, sacc[nt], 0, 0, 0);
            sacc[nt] = __builtin_amdgcn_mfma_f32_16x16x32_bf16(qf1, kf1, sacc[nt], 0, 0, 0);
        }

        // ---- online softmax (C-layout: row=quad*4+r, col=l16+16nt)
        bool last = (c == tblk);
        float al[4];
        #pragma unroll
        for (int r = 0; r < 4; ++r) {
            int trow = t0 + 16 * w + quad * 4 + r;
            float vmax = -INFINITY;
            #pragma unroll
            for (int nt = 0; nt < 4; ++nt) {
                float sv = sacc[nt][r] * 0.125f;
                if (last && (j0 + 16 * nt + l16 > trow)) sv = -INFINITY;
                sacc[nt][r] = sv;
                vmax = fmaxf(vmax, sv);
            }
            vmax = fmaxf(vmax, __shfl_xor(vmax, 1));
            vmax = fmaxf(vmax, __shfl_xor(vmax, 2));
            vmax = fmaxf(vmax, __shfl_xor(vmax, 4));
            vmax = fmaxf(vmax, __shfl_xor(vmax, 8));
            float mnew = fmaxf(mrow[r], vmax);
            al[r] = __expf(mrow[r] - mnew);
            mrow[r] = mnew;
            float rsum = 0.0f;
            #pragma unroll
            for (int nt = 0; nt < 4; ++nt) {
                float p = __expf(sacc[nt][r] - mnew);
                sP[w][quad * 4 + r][16 * nt + l16] = f2bs(p);
                rsum += p;
            }
            rsum += __shfl_xor(rsum, 1);
            rsum += __shfl_xor(rsum, 2);
            rsum += __shfl_xor(rsum, 4);
            rsum += __shfl_xor(rsum, 8);
            lrow[r] = lrow[r] * al[r] + rsum;
        }
        #pragma unroll
        for (int dt = 0; dt < 4; ++dt) {
            f32x4 o = oacc[dt];
            o[0] *= al[0]; o[1] *= al[1]; o[2] *= al[2]; o[3] *= al[3];
            oacc[dt] = o;
        }

        // ---- PV: P from sP (A-layout), V^T from sVt (B-layout)
        short8_t pf0 = *(const short8_t*)&sP[w][l16][quad * 8];
        short8_t pf1 = *(const short8_t*)&sP[w][l16][quad * 8 + 32];
        #pragma unroll
        for (int dt = 0; dt < 4; ++dt) {
            short8_t vf0 = *(const short8_t*)&sVt[l16 + 16 * dt][quad * 8];
            short8_t vf1 = *(const short8_t*)&sVt[l16 + 16 * dt][quad * 8 + 32];
            oacc[dt] = __builtin_amdgcn_mfma_f32_16x16x32_bf16(pf0, vf0, oacc[dt], 0, 0, 0);
            oacc[dt] = __builtin_amdgcn_mfma_f32_16x16x32_bf16(pf1, vf1, oacc[dt], 0, 0, 0);
        }
        __syncthreads();
    }

    // ---- epilogue: O[b,t,h*64+d] = oacc/l  (D-layout: row=quad*4+r, col=l16+16dt)
    #pragma unroll
    for (int dt = 0; dt < 4; ++dt) {
        #pragma unroll
        for (int r = 0; r < 4; ++r) {
            int t = t0 + 16 * w + quad * 4 + r;
            float o = oacc[dt][r] / lrow[r];
            O[((size_t)b * T_SEQ + t) * C_DIM + h * HD + 16 * dt + l16] = f2bs(o);
        }
    }
}

// ---------------------------------------------------------------------------
extern "C" void kernel_launch(void* const* d_in, const int* in_sizes, int n_in,
                              void* d_out, int out_size, void* d_ws, size_t ws_size,
                              hipStream_t stream)
{
    const float* x   = (const float*)d_in[0];
    const float* w_q = (const float*)d_in[1];
    const float* b_q = (const float*)d_in[2];
    const float* w_k = (const float*)d_in[3];
    const float* b_k = (const float*)d_in[4];
    const float* w_v = (const float*)d_in[5];
    const float* b_v = (const float*)d_in[6];
    const float* w_o = (const float*)d_in[7];
    const float* b_o = (const float*)d_in[8];
    float* out = (float*)d_out;

    char* ws = (char*)d_ws;
    bf16* Qb = (bf16*)(ws);                              // 8 MB
    bf16* Kb = (bf16*)(ws + ((size_t)8  << 20));         // 2 MB
    bf16* Vb = (bf16*)(ws + ((size_t)10 << 20));         // 2 MB
    bf16* Ab = (bf16*)(ws + ((size_t)12 << 20));         // 8 MB (total 20 MB)

    const int M = B_SZ * T_SEQ;   // 4096

    gemm_bias_kernel<float, bf16><<<dim3(C_DIM / 64, M / 64), 256, 0, stream>>>(
        x, w_q, b_q, Qb, M, C_DIM, C_DIM);
    gemm_bias_kernel<float, bf16><<<dim3((NKV * HD) / 64, M / 64), 256, 0, stream>>>(
        x, w_k, b_k, Kb, M, NKV * HD, C_DIM);
    gemm_bias_kernel<float, bf16><<<dim3((NKV * HD) / 64, M / 64), 256, 0, stream>>>(
        x, w_v, b_v, Vb, M, NKV * HD, C_DIM);

    {
        int pq = B_SZ * T_SEQ * NH * (HD / 2);
        rope_kernel<<<(pq + 255) / 256, 256, 0, stream>>>(Qb, NH, pq);
        int pk = B_SZ * T_SEQ * NKV * (HD / 2);
        rope_kernel<<<(pk + 255) / 256, 256, 0, stream>>>(Kb, NKV, pk);
    }

    attn_mfma_kernel<<<B_SZ * NH * (T_SEQ / 64), 256, 0, stream>>>(
        (const short*)Qb, (const short*)Kb, (const short*)Vb, (short*)Ab);

    gemm_bias_kernel<bf16, float><<<dim3(C_DIM / 64, M / 64), 256, 0, stream>>>(
        Ab, w_o, b_o, out, M, C_DIM, C_DIM);
}

// Round 5
// 333.270 us; speedup vs baseline: 8.1290x; 3.1013x over previous
//
#include <hip/hip_runtime.h>
#include <hip/hip_bf16.h>

typedef __hip_bfloat16 bf16;
typedef __attribute__((ext_vector_type(8))) short short8_t;
typedef __attribute__((ext_vector_type(4))) short short4_t;
typedef __attribute__((ext_vector_type(4))) float f32x4;

#define B_SZ   2
#define T_SEQ  2048
#define C_DIM  1024
#define NH     16
#define NKV    4
#define HD     64

// float -> bf16 bits (round-nearest-even)
__device__ __forceinline__ short f2bs(float f) {
    unsigned u = __float_as_uint(f);
    u += 0x7FFFu + ((u >> 16) & 1u);
    return (short)(u >> 16);
}
__device__ __forceinline__ float bs2f(short s) {
    unsigned u = ((unsigned)(unsigned short)s) << 16;
    return __uint_as_float(u);
}

__device__ __forceinline__ void store_c(float* p, float v) { *p = v; }
__device__ __forceinline__ void store_c(short* p, float v) { *p = f2bs(v); }

// ---------------------------------------------------------------------------
// fp32 -> bf16 bulk convert (4 elems/thread, n % 1024 == 0)
// ---------------------------------------------------------------------------
__global__ __launch_bounds__(256) void convert_f32_bf16(
    const float* __restrict__ X, short* __restrict__ Xb, int n)
{
    int i = (blockIdx.x * 256 + threadIdx.x) * 4;
    if (i >= n) return;
    float4 v = *(const float4*)(X + i);
    short4_t o;
    o[0] = f2bs(v.x); o[1] = f2bs(v.y); o[2] = f2bs(v.z); o[3] = f2bs(v.w);
    *(short4_t*)(Xb + i) = o;
}

// ---------------------------------------------------------------------------
// W[K][N] fp32 -> Wt[N][K] bf16, 32x32 LDS tile transpose, block (32,8)
// ---------------------------------------------------------------------------
__global__ __launch_bounds__(256) void transpose_f32_bf16(
    const float* __restrict__ W, short* __restrict__ Wt, int K, int N)
{
    __shared__ float tile[32][33];
    int n0 = blockIdx.x * 32, k0 = blockIdx.y * 32;
    int tx = threadIdx.x, ty = threadIdx.y;
    #pragma unroll
    for (int i = 0; i < 4; ++i)
        tile[ty + 8 * i][tx] = W[(size_t)(k0 + ty + 8 * i) * N + n0 + tx];
    __syncthreads();
    #pragma unroll
    for (int i = 0; i < 4; ++i)
        Wt[(size_t)(n0 + ty + 8 * i) * K + k0 + tx] = f2bs(tile[tx][ty + 8 * i]);
}

// ---------------------------------------------------------------------------
// MFMA GEMM (B^T input): C[M][N] = A[M][K] @ Bt[N][K]^T + bias.
// bf16 in, fp32 accumulate, CT out. 128x128 tile, BK=32, 256 thr = 4 waves,
// wave = 64x64 (4x4 tiles of 16x16x32). LDS rows padded to 40 shorts
// (stride 20 words, gcd(20,32)=4 -> 2-way bank aliasing = free).
// Layouts (verified m89/m91): A-frag A[m=l16][k=quad*8+j];
// B-frag B[k=quad*8+j][n=l16]; C/D col=l16, row=quad*4+reg.
// ---------------------------------------------------------------------------
template <typename CT>
__global__ __launch_bounds__(256) void gemm_mfma_bt(
    const short* __restrict__ A, const short* __restrict__ Bt,
    const float* __restrict__ bias, CT* __restrict__ C,
    int M, int N, int K)
{
    __shared__ short sA[128][40];
    __shared__ short sB[128][40];

    int m0 = blockIdx.y * 128;
    int n0 = blockIdx.x * 128;
    int tid  = threadIdx.x;
    int w    = tid >> 6, lane = tid & 63;
    int quad = lane >> 4, l16 = lane & 15;
    int wm = w & 1, wn = w >> 1;

    f32x4 acc[4][4] = {};

    for (int k0 = 0; k0 < K; k0 += 32) {
        #pragma unroll
        for (int it = 0; it < 2; ++it) {
            int slot = tid + 256 * it;
            int row = slot >> 2, g = slot & 3;
            *(short8_t*)&sA[row][g * 8] =
                *(const short8_t*)(A + (size_t)(m0 + row) * K + k0 + g * 8);
        }
        #pragma unroll
        for (int it = 0; it < 2; ++it) {
            int slot = tid + 256 * it;
            int row = slot >> 2, g = slot & 3;
            *(short8_t*)&sB[row][g * 8] =
                *(const short8_t*)(Bt + (size_t)(n0 + row) * K + k0 + g * 8);
        }
        __syncthreads();

        short8_t af[4], bf[4];
        #pragma unroll
        for (int mt = 0; mt < 4; ++mt)
            af[mt] = *(const short8_t*)&sA[wm * 64 + mt * 16 + l16][quad * 8];
        #pragma unroll
        for (int nt = 0; nt < 4; ++nt)
            bf[nt] = *(const short8_t*)&sB[wn * 64 + nt * 16 + l16][quad * 8];
        #pragma unroll
        for (int mt = 0; mt < 4; ++mt)
            #pragma unroll
            for (int nt = 0; nt < 4; ++nt)
                acc[mt][nt] = __builtin_amdgcn_mfma_f32_16x16x32_bf16(
                    af[mt], bf[nt], acc[mt][nt], 0, 0, 0);
        __syncthreads();
    }

    #pragma unroll
    for (int mt = 0; mt < 4; ++mt) {
        #pragma unroll
        for (int nt = 0; nt < 4; ++nt) {
            int col = n0 + wn * 64 + nt * 16 + l16;
            float bv = bias[col];
            #pragma unroll
            for (int r = 0; r < 4; ++r) {
                int row = m0 + wm * 64 + mt * 16 + quad * 4 + r;
                store_c(&C[(size_t)row * N + col], acc[mt][nt][r] + bv);
            }
        }
    }
}

// ---------------------------------------------------------------------------
// RoPE (interleaved pairs), in-place on bf16-bits [B*T, n_heads*64] rows.
// ---------------------------------------------------------------------------
__global__ void rope_kernel(short* __restrict__ X, int n_heads, int total_pairs)
{
    int p = blockIdx.x * blockDim.x + threadIdx.x;
    if (p >= total_pairs) return;
    int i = p & 31;
    int r = p >> 5;
    int t = (r / n_heads) % T_SEQ;

    size_t base = (size_t)r * HD + 2 * i;
    float e = bs2f(X[base]);
    float o = bs2f(X[base + 1]);

    float freq = powf(10000.0f, -(float)(2 * i) / 64.0f);
    float ang  = (float)t * freq;
    float cs = cosf(ang);
    float sn = sinf(ang);

    X[base]     = f2bs(e * cs - o * sn);
    X[base + 1] = f2bs(e * sn + o * cs);
}

// ---------------------------------------------------------------------------
// MFMA flash attention (unchanged from round 4 — verified).
// ---------------------------------------------------------------------------
__global__ __launch_bounds__(256) void attn_mfma_kernel(
    const short* __restrict__ Q, const short* __restrict__ K,
    const short* __restrict__ V, short* __restrict__ O)
{
    __shared__ short sK [64][72];
    __shared__ short sVt[64][72];
    __shared__ short sP [4][16][72];

    const int tid  = threadIdx.x;
    const int w    = tid >> 6;
    const int lane = tid & 63;
    const int quad = lane >> 4;
    const int l16  = lane & 15;

    const int nT   = T_SEQ / 64;
    int blk  = blockIdx.x;
    int tblk = nT - 1 - (blk % nT);
    int bh   = blk / nT;
    int h    = bh % NH;
    int b    = bh / NH;
    int t0   = tblk * 64;
    int kvh  = h >> 2;

    const short* qptr = Q + (((size_t)b * T_SEQ + t0 + 16 * w + l16) * NH + h) * HD;
    short8_t qf0 = *(const short8_t*)(qptr + quad * 8);
    short8_t qf1 = *(const short8_t*)(qptr + quad * 8 + 32);

    const short* kptr = K + ((size_t)b * T_SEQ * NKV + kvh) * HD;
    const short* vptr = V + ((size_t)b * T_SEQ * NKV + kvh) * HD;

    float mrow[4], lrow[4];
    f32x4 oacc[4];
    #pragma unroll
    for (int r = 0; r < 4; ++r) { mrow[r] = -INFINITY; lrow[r] = 0.0f; }
    #pragma unroll
    for (int dt = 0; dt < 4; ++dt) oacc[dt] = (f32x4){0.f, 0.f, 0.f, 0.f};

    for (int c = 0; c <= tblk; ++c) {
        int j0 = c * 64;

        #pragma unroll
        for (int it = 0; it < 2; ++it) {
            int slot = tid + 256 * it;
            int key  = slot >> 3;
            int d0   = (slot & 7) * 8;
            *(short8_t*)&sK[key][d0] =
                *(const short8_t*)(kptr + (size_t)(j0 + key) * (NKV * HD) + d0);
        }
        #pragma unroll
        for (int it = 0; it < 2; ++it) {
            int slot = tid + 256 * it;
            int key  = slot & 63;
            int d0   = (slot >> 6) * 8;
            short8_t v = *(const short8_t*)(vptr + (size_t)(j0 + key) * (NKV * HD) + d0);
            #pragma unroll
            for (int i = 0; i < 8; ++i) sVt[d0 + i][key] = v[i];
        }
        __syncthreads();

        f32x4 sacc[4];
        #pragma unroll
        for (int nt = 0; nt < 4; ++nt) sacc[nt] = (f32x4){0.f, 0.f, 0.f, 0.f};
        #pragma unroll
        for (int nt = 0; nt < 4; ++nt) {
            short8_t kf0 = *(const short8_t*)&sK[l16 + 16 * nt][quad * 8];
            short8_t kf1 = *(const short8_t*)&sK[l16 + 16 * nt][quad * 8 + 32];
            sacc[nt] = __builtin_amdgcn_mfma_f32_16x16x32_bf16(qf0, kf0, sacc[nt], 0, 0, 0);
            sacc[nt] = __builtin_amdgcn_mfma_f32_16x16x32_bf16(qf1, kf1, sacc[nt], 0, 0, 0);
        }

        bool last = (c == tblk);
        float al[4];
        #pragma unroll
        for (int r = 0; r < 4; ++r) {
            int trow = t0 + 16 * w + quad * 4 + r;
            float vmax = -INFINITY;
            #pragma unroll
            for (int nt = 0; nt < 4; ++nt) {
                float sv = sacc[nt][r] * 0.125f;
                if (last && (j0 + 16 * nt + l16 > trow)) sv = -INFINITY;
                sacc[nt][r] = sv;
                vmax = fmaxf(vmax, sv);
            }
            vmax = fmaxf(vmax, __shfl_xor(vmax, 1));
            vmax = fmaxf(vmax, __shfl_xor(vmax, 2));
            vmax = fmaxf(vmax, __shfl_xor(vmax, 4));
            vmax = fmaxf(vmax, __shfl_xor(vmax, 8));
            float mnew = fmaxf(mrow[r], vmax);
            al[r] = __expf(mrow[r] - mnew);
            mrow[r] = mnew;
            float rsum = 0.0f;
            #pragma unroll
            for (int nt = 0; nt < 4; ++nt) {
                float p = __expf(sacc[nt][r] - mnew);
                sP[w][quad * 4 + r][16 * nt + l16] = f2bs(p);
                rsum += p;
            }
            rsum += __shfl_xor(rsum, 1);
            rsum += __shfl_xor(rsum, 2);
            rsum += __shfl_xor(rsum, 4);
            rsum += __shfl_xor(rsum, 8);
            lrow[r] = lrow[r] * al[r] + rsum;
        }
        #pragma unroll
        for (int dt = 0; dt < 4; ++dt) {
            f32x4 o = oacc[dt];
            o[0] *= al[0]; o[1] *= al[1]; o[2] *= al[2]; o[3] *= al[3];
            oacc[dt] = o;
        }

        short8_t pf0 = *(const short8_t*)&sP[w][l16][quad * 8];
        short8_t pf1 = *(const short8_t*)&sP[w][l16][quad * 8 + 32];
        #pragma unroll
        for (int dt = 0; dt < 4; ++dt) {
            short8_t vf0 = *(const short8_t*)&sVt[l16 + 16 * dt][quad * 8];
            short8_t vf1 = *(const short8_t*)&sVt[l16 + 16 * dt][quad * 8 + 32];
            oacc[dt] = __builtin_amdgcn_mfma_f32_16x16x32_bf16(pf0, vf0, oacc[dt], 0, 0, 0);
            oacc[dt] = __builtin_amdgcn_mfma_f32_16x16x32_bf16(pf1, vf1, oacc[dt], 0, 0, 0);
        }
        __syncthreads();
    }

    #pragma unroll
    for (int dt = 0; dt < 4; ++dt) {
        #pragma unroll
        for (int r = 0; r < 4; ++r) {
            int t = t0 + 16 * w + quad * 4 + r;
            float o = oacc[dt][r] / lrow[r];
            O[((size_t)b * T_SEQ + t) * C_DIM + h * HD + 16 * dt + l16] = f2bs(o);
        }
    }
}

// ---------------------------------------------------------------------------
extern "C" void kernel_launch(void* const* d_in, const int* in_sizes, int n_in,
                              void* d_out, int out_size, void* d_ws, size_t ws_size,
                              hipStream_t stream)
{
    const float* x   = (const float*)d_in[0];
    const float* w_q = (const float*)d_in[1];
    const float* b_q = (const float*)d_in[2];
    const float* w_k = (const float*)d_in[3];
    const float* b_k = (const float*)d_in[4];
    const float* w_v = (const float*)d_in[5];
    const float* b_v = (const float*)d_in[6];
    const float* w_o = (const float*)d_in[7];
    const float* b_o = (const float*)d_in[8];
    float* out = (float*)d_out;

    char* ws = (char*)d_ws;
    short* Qb  = (short*)(ws);                        // 8 MB
    short* Kb  = (short*)(ws + ((size_t)8  << 20));   // 2 MB
    short* Vb  = (short*)(ws + ((size_t)10 << 20));   // 2 MB
    short* Ab  = (short*)(ws + ((size_t)12 << 20));   // 8 MB
    short* Xb  = (short*)(ws + ((size_t)20 << 20));   // 8 MB
    short* Wtq = (short*)(ws + ((size_t)28 << 20));   // 2 MB
    short* Wtk = (short*)(ws + ((size_t)30 << 20));   // 0.5 MB
    short* Wtv = (short*)(ws + ((size_t)31 << 20));   // 0.5 MB
    short* Wto = (short*)(ws + ((size_t)32 << 20));   // 2 MB (total 34 MB)

    const int M   = B_SZ * T_SEQ;   // 4096
    const int KVC = NKV * HD;       // 256

    // prep: bf16 conversions + weight transposes
    convert_f32_bf16<<<(M * C_DIM / 4 + 255) / 256, 256, 0, stream>>>(
        x, Xb, M * C_DIM);
    transpose_f32_bf16<<<dim3(C_DIM / 32, C_DIM / 32), dim3(32, 8), 0, stream>>>(
        w_q, Wtq, C_DIM, C_DIM);
    transpose_f32_bf16<<<dim3(KVC / 32, C_DIM / 32), dim3(32, 8), 0, stream>>>(
        w_k, Wtk, C_DIM, KVC);
    transpose_f32_bf16<<<dim3(KVC / 32, C_DIM / 32), dim3(32, 8), 0, stream>>>(
        w_v, Wtv, C_DIM, KVC);
    transpose_f32_bf16<<<dim3(C_DIM / 32, C_DIM / 32), dim3(32, 8), 0, stream>>>(
        w_o, Wto, C_DIM, C_DIM);

    // projections (MFMA)
    gemm_mfma_bt<short><<<dim3(C_DIM / 128, M / 128), 256, 0, stream>>>(
        Xb, Wtq, b_q, Qb, M, C_DIM, C_DIM);
    gemm_mfma_bt<short><<<dim3(KVC / 128, M / 128), 256, 0, stream>>>(
        Xb, Wtk, b_k, Kb, M, KVC, C_DIM);
    gemm_mfma_bt<short><<<dim3(KVC / 128, M / 128), 256, 0, stream>>>(
        Xb, Wtv, b_v, Vb, M, KVC, C_DIM);

    // RoPE
    {
        int pq = B_SZ * T_SEQ * NH * (HD / 2);
        rope_kernel<<<(pq + 255) / 256, 256, 0, stream>>>(Qb, NH, pq);
        int pk = B_SZ * T_SEQ * NKV * (HD / 2);
        rope_kernel<<<(pk + 255) / 256, 256, 0, stream>>>(Kb, NKV, pk);
    }

    // attention
    attn_mfma_kernel<<<B_SZ * NH * (T_SEQ / 64), 256, 0, stream>>>(
        Qb, Kb, Vb, Ab);

    // output projection (fp32 out)
    gemm_mfma_bt<float><<<dim3(C_DIM / 128, M / 128), 256, 0, stream>>>(
        Ab, Wto, b_o, out, M, C_DIM, C_DIM);
}

// Round 6
// 273.489 us; speedup vs baseline: 9.9059x; 1.2186x over previous
//
#include <hip/hip_runtime.h>
#include <hip/hip_bf16.h>

typedef __hip_bfloat16 bf16;
typedef __attribute__((ext_vector_type(8))) short short8_t;
typedef __attribute__((ext_vector_type(4))) short short4_t;
typedef __attribute__((ext_vector_type(4))) float f32x4;

#define B_SZ   2
#define T_SEQ  2048
#define C_DIM  1024
#define NH     16
#define NKV    4
#define HD     64

// float -> bf16 bits (round-nearest-even)
__device__ __forceinline__ short f2bs(float f) {
    unsigned u = __float_as_uint(f);
    u += 0x7FFFu + ((u >> 16) & 1u);
    return (short)(u >> 16);
}
__device__ __forceinline__ float bs2f(short s) {
    unsigned u = ((unsigned)(unsigned short)s) << 16;
    return __uint_as_float(u);
}

__device__ __forceinline__ void store_c(float* p, float v) { *p = v; }
__device__ __forceinline__ void store_c(short* p, float v) { *p = f2bs(v); }

// max over each 16-lane row via DPP (xor1, xor2, xor7, xor15) — pure VALU,
// replaces ds_swizzle-based __shfl_xor chains.
__device__ __forceinline__ float dpp_max16(float x) {
    int t;
    t = __builtin_amdgcn_update_dpp(0, __float_as_int(x), 0xB1, 0xF, 0xF, true);  // quad_perm [1,0,3,2]
    x = fmaxf(x, __int_as_float(t));
    t = __builtin_amdgcn_update_dpp(0, __float_as_int(x), 0x4E, 0xF, 0xF, true);  // quad_perm [2,3,0,1]
    x = fmaxf(x, __int_as_float(t));
    t = __builtin_amdgcn_update_dpp(0, __float_as_int(x), 0x141, 0xF, 0xF, true); // row_half_mirror (xor7)
    x = fmaxf(x, __int_as_float(t));
    t = __builtin_amdgcn_update_dpp(0, __float_as_int(x), 0x140, 0xF, 0xF, true); // row_mirror (xor15)
    x = fmaxf(x, __int_as_float(t));
    return x;
}

// ---------------------------------------------------------------------------
// fp32 -> bf16 bulk convert (4 elems/thread, n % 1024 == 0)
// ---------------------------------------------------------------------------
__global__ __launch_bounds__(256) void convert_f32_bf16(
    const float* __restrict__ X, short* __restrict__ Xb, int n)
{
    int i = (blockIdx.x * 256 + threadIdx.x) * 4;
    if (i >= n) return;
    float4 v = *(const float4*)(X + i);
    short4_t o;
    o[0] = f2bs(v.x); o[1] = f2bs(v.y); o[2] = f2bs(v.z); o[3] = f2bs(v.w);
    *(short4_t*)(Xb + i) = o;
}

// ---------------------------------------------------------------------------
// W[K][N] fp32 -> Wt[N][K] bf16, 32x32 LDS tile transpose, block (32,8)
// ---------------------------------------------------------------------------
__global__ __launch_bounds__(256) void transpose_f32_bf16(
    const float* __restrict__ W, short* __restrict__ Wt, int K, int N)
{
    __shared__ float tile[32][33];
    int n0 = blockIdx.x * 32, k0 = blockIdx.y * 32;
    int tx = threadIdx.x, ty = threadIdx.y;
    #pragma unroll
    for (int i = 0; i < 4; ++i)
        tile[ty + 8 * i][tx] = W[(size_t)(k0 + ty + 8 * i) * N + n0 + tx];
    __syncthreads();
    #pragma unroll
    for (int i = 0; i < 4; ++i)
        Wt[(size_t)(n0 + ty + 8 * i) * K + k0 + tx] = f2bs(tile[tx][ty + 8 * i]);
}

// ---------------------------------------------------------------------------
// MFMA GEMM (B^T input): C[M][N] = A[M][K] @ Bt[N][K]^T + bias. (round-5, works)
// ---------------------------------------------------------------------------
template <typename CT>
__global__ __launch_bounds__(256) void gemm_mfma_bt(
    const short* __restrict__ A, const short* __restrict__ Bt,
    const float* __restrict__ bias, CT* __restrict__ C,
    int M, int N, int K)
{
    __shared__ short sA[128][40];
    __shared__ short sB[128][40];

    int m0 = blockIdx.y * 128;
    int n0 = blockIdx.x * 128;
    int tid  = threadIdx.x;
    int w    = tid >> 6, lane = tid & 63;
    int quad = lane >> 4, l16 = lane & 15;
    int wm = w & 1, wn = w >> 1;

    f32x4 acc[4][4] = {};

    for (int k0 = 0; k0 < K; k0 += 32) {
        #pragma unroll
        for (int it = 0; it < 2; ++it) {
            int slot = tid + 256 * it;
            int row = slot >> 2, g = slot & 3;
            *(short8_t*)&sA[row][g * 8] =
                *(const short8_t*)(A + (size_t)(m0 + row) * K + k0 + g * 8);
        }
        #pragma unroll
        for (int it = 0; it < 2; ++it) {
            int slot = tid + 256 * it;
            int row = slot >> 2, g = slot & 3;
            *(short8_t*)&sB[row][g * 8] =
                *(const short8_t*)(Bt + (size_t)(n0 + row) * K + k0 + g * 8);
        }
        __syncthreads();

        short8_t af[4], bf[4];
        #pragma unroll
        for (int mt = 0; mt < 4; ++mt)
            af[mt] = *(const short8_t*)&sA[wm * 64 + mt * 16 + l16][quad * 8];
        #pragma unroll
        for (int nt = 0; nt < 4; ++nt)
            bf[nt] = *(const short8_t*)&sB[wn * 64 + nt * 16 + l16][quad * 8];
        #pragma unroll
        for (int mt = 0; mt < 4; ++mt)
            #pragma unroll
            for (int nt = 0; nt < 4; ++nt)
                acc[mt][nt] = __builtin_amdgcn_mfma_f32_16x16x32_bf16(
                    af[mt], bf[nt], acc[mt][nt], 0, 0, 0);
        __syncthreads();
    }

    #pragma unroll
    for (int mt = 0; mt < 4; ++mt) {
        #pragma unroll
        for (int nt = 0; nt < 4; ++nt) {
            int col = n0 + wn * 64 + nt * 16 + l16;
            float bv = bias[col];
            #pragma unroll
            for (int r = 0; r < 4; ++r) {
                int row = m0 + wm * 64 + mt * 16 + quad * 4 + r;
                store_c(&C[(size_t)row * N + col], acc[mt][nt][r] + bv);
            }
        }
    }
}

// ---------------------------------------------------------------------------
// RoPE (interleaved pairs), in-place on bf16-bits [B*T, n_heads*64] rows.
// ---------------------------------------------------------------------------
__global__ void rope_kernel(short* __restrict__ X, int n_heads, int total_pairs)
{
    int p = blockIdx.x * blockDim.x + threadIdx.x;
    if (p >= total_pairs) return;
    int i = p & 31;
    int r = p >> 5;
    int t = (r / n_heads) % T_SEQ;

    size_t base = (size_t)r * HD + 2 * i;
    float e = bs2f(X[base]);
    float o = bs2f(X[base + 1]);

    float freq = powf(10000.0f, -(float)(2 * i) / 64.0f);
    float ang  = (float)t * freq;
    float cs = cosf(ang);
    float sn = sinf(ang);

    X[base]     = f2bs(e * cs - o * sn);
    X[base + 1] = f2bs(e * sn + o * cs);
}

// ---------------------------------------------------------------------------
// MFMA flash attention v2.
//   Block = (b, kvh, pair p). 4 waves = the 4 GQA heads sharing kv head kvh.
//   Each wave processes TWO 16-row q-tiles: tqA = p, tqB = 127-p -> every
//   block does a constant ~33 tile-chunks (perfect balance, grid=512).
//   K/V staged once per 64-key chunk, shared by all 4 waves; chunk c+1
//   prefetched into registers under compute. Softmax: DPP max + MFMA row-sum.
// ---------------------------------------------------------------------------
__device__ __forceinline__ void attn_step(
    int tq, int c, bool maskc, int quad, int l16,
    short8_t qf0, short8_t qf1,
    const short (*sK)[72], const short (*sVt)[72], short (*sPw)[72],
    float (&mrow)[4], float (&lrow)[4], f32x4 (&oacc)[4], short8_t ones)
{
    f32x4 sacc[4];
    #pragma unroll
    for (int nt = 0; nt < 4; ++nt) {
        f32x4 z = {0.f, 0.f, 0.f, 0.f};
        short8_t kf0 = *(const short8_t*)&sK[l16 + 16 * nt][quad * 8];
        short8_t kf1 = *(const short8_t*)&sK[l16 + 16 * nt][quad * 8 + 32];
        z = __builtin_amdgcn_mfma_f32_16x16x32_bf16(qf0, kf0, z, 0, 0, 0);
        z = __builtin_amdgcn_mfma_f32_16x16x32_bf16(qf1, kf1, z, 0, 0, 0);
        sacc[nt] = z;
    }
    int j0 = c * 64;
    #pragma unroll
    for (int r = 0; r < 4; ++r) {
        int m = quad * 4 + r;
        int trow = tq * 16 + m;
        float sv[4], vmax = -INFINITY;
        #pragma unroll
        for (int nt = 0; nt < 4; ++nt) {
            float s = sacc[nt][r] * 0.125f;
            if (maskc && (j0 + 16 * nt + l16 > trow)) s = -INFINITY;
            sv[nt] = s;
            vmax = fmaxf(vmax, s);
        }
        vmax = dpp_max16(vmax);
        float mnew = fmaxf(mrow[r], vmax);
        float al = __expf(mrow[r] - mnew);
        mrow[r] = mnew;
        #pragma unroll
        for (int nt = 0; nt < 4; ++nt)
            sPw[m][16 * nt + l16] = f2bs(__expf(sv[nt] - mnew));
        lrow[r] *= al;
        #pragma unroll
        for (int dt = 0; dt < 4; ++dt) oacc[dt][r] *= al;
    }
    short8_t pf0 = *(const short8_t*)&sPw[l16][quad * 8];
    short8_t pf1 = *(const short8_t*)&sPw[l16][quad * 8 + 32];
    f32x4 rs = {0.f, 0.f, 0.f, 0.f};
    rs = __builtin_amdgcn_mfma_f32_16x16x32_bf16(pf0, ones, rs, 0, 0, 0);
    rs = __builtin_amdgcn_mfma_f32_16x16x32_bf16(pf1, ones, rs, 0, 0, 0);
    #pragma unroll
    for (int r = 0; r < 4; ++r) lrow[r] += rs[r];
    #pragma unroll
    for (int dt = 0; dt < 4; ++dt) {
        short8_t vf0 = *(const short8_t*)&sVt[l16 + 16 * dt][quad * 8];
        short8_t vf1 = *(const short8_t*)&sVt[l16 + 16 * dt][quad * 8 + 32];
        oacc[dt] = __builtin_amdgcn_mfma_f32_16x16x32_bf16(pf0, vf0, oacc[dt], 0, 0, 0);
        oacc[dt] = __builtin_amdgcn_mfma_f32_16x16x32_bf16(pf1, vf1, oacc[dt], 0, 0, 0);
    }
}

__global__ __launch_bounds__(256) void attn_mfma2(
    const short* __restrict__ Q, const short* __restrict__ K,
    const short* __restrict__ V, short* __restrict__ O)
{
    __shared__ short sK [64][72];
    __shared__ short sVt[64][72];
    __shared__ short sP [4][16][72];

    const int tid  = threadIdx.x;
    const int w    = tid >> 6;
    const int lane = tid & 63;
    const int quad = lane >> 4;
    const int l16  = lane & 15;

    int blk = blockIdx.x;
    int p   = blk & 63;
    int bk  = blk >> 6;
    int kvh = bk & 3;
    int b   = bk >> 2;
    int h   = kvh * 4 + w;                 // wave -> head within the GQA group
    int tqA = p, tqB = 127 - p;            // paired 16-row q tiles
    int ctA = tqA >> 2, ctB = tqB >> 2;    // last chunk index per tile

    const short* qA = Q + (((size_t)b * T_SEQ + tqA * 16 + l16) * NH + h) * HD;
    const short* qB = Q + (((size_t)b * T_SEQ + tqB * 16 + l16) * NH + h) * HD;
    short8_t qA0 = *(const short8_t*)(qA + quad * 8);
    short8_t qA1 = *(const short8_t*)(qA + quad * 8 + 32);
    short8_t qB0 = *(const short8_t*)(qB + quad * 8);
    short8_t qB1 = *(const short8_t*)(qB + quad * 8 + 32);

    const short* kptr = K + ((size_t)b * T_SEQ * NKV + kvh) * HD;
    const short* vptr = V + ((size_t)b * T_SEQ * NKV + kvh) * HD;

    short8_t ones;
    #pragma unroll
    for (int i = 0; i < 8; ++i) ones[i] = (short)0x3F80;

    float mA[4], lA[4], mB[4], lB[4];
    f32x4 oA[4], oB[4];
    #pragma unroll
    for (int r = 0; r < 4; ++r) {
        mA[r] = -INFINITY; lA[r] = 0.f;
        mB[r] = -INFINITY; lB[r] = 0.f;
    }
    #pragma unroll
    for (int dt = 0; dt < 4; ++dt) {
        oA[dt] = (f32x4){0.f, 0.f, 0.f, 0.f};
        oB[dt] = (f32x4){0.f, 0.f, 0.f, 0.f};
    }

    const int kkey = tid >> 3, kd = (tid & 7) * 8;   // K staging: 8 lanes/key
    const int vkey = tid & 63, vd = (tid >> 6) * 8;  // V staging: lane/key

    short8_t kr[2], vr[2];
    {
        #pragma unroll
        for (int it = 0; it < 2; ++it) {
            kr[it] = *(const short8_t*)(kptr + (size_t)(kkey + 32 * it) * (NKV * HD) + kd);
            vr[it] = *(const short8_t*)(vptr + (size_t)vkey * (NKV * HD) + vd + 32 * it);
        }
    }

    for (int c = 0; c <= ctB; ++c) {
        __syncthreads();     // previous chunk's LDS reads done
        #pragma unroll
        for (int it = 0; it < 2; ++it) {
            *(short8_t*)&sK[kkey + 32 * it][kd] = kr[it];
            #pragma unroll
            for (int i = 0; i < 8; ++i) sVt[vd + 32 * it + i][vkey] = vr[it][i];
        }
        __syncthreads();
        if (c < ctB) {       // prefetch chunk c+1 under compute
            int j0 = (c + 1) * 64;
            #pragma unroll
            for (int it = 0; it < 2; ++it) {
                kr[it] = *(const short8_t*)(kptr + (size_t)(j0 + kkey + 32 * it) * (NKV * HD) + kd);
                vr[it] = *(const short8_t*)(vptr + (size_t)(j0 + vkey) * (NKV * HD) + vd + 32 * it);
            }
        }
        attn_step(tqB, c, c == ctB, quad, l16, qB0, qB1, sK, sVt, sP[w], mB, lB, oB, ones);
        if (c <= ctA)
            attn_step(tqA, c, c == ctA, quad, l16, qA0, qA1, sK, sVt, sP[w], mA, lA, oA, ones);
    }

    #pragma unroll
    for (int r = 0; r < 4; ++r) {
        int m = quad * 4 + r;
        float invA = __builtin_amdgcn_rcpf(lA[r]);
        float invB = __builtin_amdgcn_rcpf(lB[r]);
        #pragma unroll
        for (int dt = 0; dt < 4; ++dt) {
            O[((size_t)b * T_SEQ + tqA * 16 + m) * C_DIM + h * HD + 16 * dt + l16] =
                f2bs(oA[dt][r] * invA);
            O[((size_t)b * T_SEQ + tqB * 16 + m) * C_DIM + h * HD + 16 * dt + l16] =
                f2bs(oB[dt][r] * invB);
        }
    }
}

// ---------------------------------------------------------------------------
extern "C" void kernel_launch(void* const* d_in, const int* in_sizes, int n_in,
                              void* d_out, int out_size, void* d_ws, size_t ws_size,
                              hipStream_t stream)
{
    const float* x   = (const float*)d_in[0];
    const float* w_q = (const float*)d_in[1];
    const float* b_q = (const float*)d_in[2];
    const float* w_k = (const float*)d_in[3];
    const float* b_k = (const float*)d_in[4];
    const float* w_v = (const float*)d_in[5];
    const float* b_v = (const float*)d_in[6];
    const float* w_o = (const float*)d_in[7];
    const float* b_o = (const float*)d_in[8];
    float* out = (float*)d_out;

    char* ws = (char*)d_ws;
    short* Qb  = (short*)(ws);                        // 8 MB
    short* Kb  = (short*)(ws + ((size_t)8  << 20));   // 2 MB
    short* Vb  = (short*)(ws + ((size_t)10 << 20));   // 2 MB
    short* Ab  = (short*)(ws + ((size_t)12 << 20));   // 8 MB
    short* Xb  = (short*)(ws + ((size_t)20 << 20));   // 8 MB
    short* Wtq = (short*)(ws + ((size_t)28 << 20));   // 2 MB
    short* Wtk = (short*)(ws + ((size_t)30 << 20));   // 0.5 MB
    short* Wtv = (short*)(ws + ((size_t)31 << 20));   // 0.5 MB
    short* Wto = (short*)(ws + ((size_t)32 << 20));   // 2 MB (total 34 MB)

    const int M   = B_SZ * T_SEQ;   // 4096
    const int KVC = NKV * HD;       // 256

    convert_f32_bf16<<<(M * C_DIM / 4 + 255) / 256, 256, 0, stream>>>(
        x, Xb, M * C_DIM);
    transpose_f32_bf16<<<dim3(C_DIM / 32, C_DIM / 32), dim3(32, 8), 0, stream>>>(
        w_q, Wtq, C_DIM, C_DIM);
    transpose_f32_bf16<<<dim3(KVC / 32, C_DIM / 32), dim3(32, 8), 0, stream>>>(
        w_k, Wtk, C_DIM, KVC);
    transpose_f32_bf16<<<dim3(KVC / 32, C_DIM / 32), dim3(32, 8), 0, stream>>>(
        w_v, Wtv, C_DIM, KVC);
    transpose_f32_bf16<<<dim3(C_DIM / 32, C_DIM / 32), dim3(32, 8), 0, stream>>>(
        w_o, Wto, C_DIM, C_DIM);

    gemm_mfma_bt<short><<<dim3(C_DIM / 128, M / 128), 256, 0, stream>>>(
        Xb, Wtq, b_q, Qb, M, C_DIM, C_DIM);
    gemm_mfma_bt<short><<<dim3(KVC / 128, M / 128), 256, 0, stream>>>(
        Xb, Wtk, b_k, Kb, M, KVC, C_DIM);
    gemm_mfma_bt<short><<<dim3(KVC / 128, M / 128), 256, 0, stream>>>(
        Xb, Wtv, b_v, Vb, M, KVC, C_DIM);

    {
        int pq = B_SZ * T_SEQ * NH * (HD / 2);
        rope_kernel<<<(pq + 255) / 256, 256, 0, stream>>>(Qb, NH, pq);
        int pk = B_SZ * T_SEQ * NKV * (HD / 2);
        rope_kernel<<<(pk + 255) / 256, 256, 0, stream>>>(Kb, NKV, pk);
    }

    attn_mfma2<<<B_SZ * NKV * 64, 256, 0, stream>>>(Qb, Kb, Vb, Ab);

    gemm_mfma_bt<float><<<dim3(C_DIM / 128, M / 128), 256, 0, stream>>>(
        Ab, Wto, b_o, out, M, C_DIM, C_DIM);
}

// Round 7
// 206.815 us; speedup vs baseline: 13.0994x; 1.3224x over previous
//
#include <hip/hip_runtime.h>
#include <hip/hip_bf16.h>

typedef __hip_bfloat16 bf16;
typedef __attribute__((ext_vector_type(8))) short short8_t;
typedef __attribute__((ext_vector_type(4))) short short4_t;
typedef __attribute__((ext_vector_type(4))) float f32x4;

#define B_SZ   2
#define T_SEQ  2048
#define C_DIM  1024
#define NH     16
#define NKV    4
#define HD     64
#define QKVW   1536          // fused QKV row width (1024 Q | 256 K | 256 V)

// float -> bf16 bits (round-nearest-even)
__device__ __forceinline__ short f2bs(float f) {
    unsigned u = __float_as_uint(f);
    u += 0x7FFFu + ((u >> 16) & 1u);
    return (short)(u >> 16);
}
// float -> bf16 bits (truncate) — for P tiles, consistent num/denom
__device__ __forceinline__ short f2bs_trunc(float f) {
    return (short)(__float_as_uint(f) >> 16);
}
__device__ __forceinline__ float bs2f(short s) {
    unsigned u = ((unsigned)(unsigned short)s) << 16;
    return __uint_as_float(u);
}

__device__ __forceinline__ void store_c(float* p, float v) { *p = v; }
__device__ __forceinline__ void store_c(short* p, float v) { *p = f2bs(v); }

// max over each 16-lane row via DPP (xor1, xor2, xor7, xor15) — pure VALU
__device__ __forceinline__ float dpp_max16(float x) {
    int t;
    t = __builtin_amdgcn_update_dpp(0, __float_as_int(x), 0xB1, 0xF, 0xF, true);  // quad_perm [1,0,3,2]
    x = fmaxf(x, __int_as_float(t));
    t = __builtin_amdgcn_update_dpp(0, __float_as_int(x), 0x4E, 0xF, 0xF, true);  // quad_perm [2,3,0,1]
    x = fmaxf(x, __int_as_float(t));
    t = __builtin_amdgcn_update_dpp(0, __float_as_int(x), 0x141, 0xF, 0xF, true); // row_half_mirror
    x = fmaxf(x, __int_as_float(t));
    t = __builtin_amdgcn_update_dpp(0, __float_as_int(x), 0x140, 0xF, 0xF, true); // row_mirror
    x = fmaxf(x, __int_as_float(t));
    return x;
}

// ---------------------------------------------------------------------------
// Fused prep: x->bf16 convert, 4 weight transposes (into fused QKV layout +
// Wto), bias concat. One dispatch, 6662 independent blocks of 256 threads.
//   blocks [0,4096)        : convert x (1024 elems each)
//   [4096,5120)            : w_q  -> Wqkv rows 0..1024
//   [5120,5376)            : w_k  -> Wqkv rows 1024..1280
//   [5376,5632)            : w_v  -> Wqkv rows 1280..1536
//   [5632,6656)            : w_o  -> Wto
//   [6656,6662)            : bias concat -> Bqkv[1536]
// ---------------------------------------------------------------------------
__device__ __forceinline__ void transpose_tile(
    const float* __restrict__ W, short* __restrict__ Wt,
    int K, int N, int n0, int k0, int tid)
{
    __shared__ float tile[32][33];
    int tx = tid & 31, ty = tid >> 5;   // (32,8)
    #pragma unroll
    for (int i = 0; i < 4; ++i)
        tile[ty + 8 * i][tx] = W[(size_t)(k0 + ty + 8 * i) * N + n0 + tx];
    __syncthreads();
    #pragma unroll
    for (int i = 0; i < 4; ++i)
        Wt[(size_t)(n0 + ty + 8 * i) * K + k0 + tx] = f2bs(tile[tx][ty + 8 * i]);
}

__global__ __launch_bounds__(256) void prep_kernel(
    const float* __restrict__ x,
    const float* __restrict__ w_q, const float* __restrict__ w_k,
    const float* __restrict__ w_v, const float* __restrict__ w_o,
    const float* __restrict__ b_q, const float* __restrict__ b_k,
    const float* __restrict__ b_v,
    short* __restrict__ Xb, short* __restrict__ Wqkv, short* __restrict__ Wto,
    float* __restrict__ Bqkv)
{
    int blk = blockIdx.x, tid = threadIdx.x;
    if (blk < 4096) {
        int i = blk * 1024 + tid * 4;
        float4 v = *(const float4*)(x + i);
        short4_t o;
        o[0] = f2bs(v.x); o[1] = f2bs(v.y); o[2] = f2bs(v.z); o[3] = f2bs(v.w);
        *(short4_t*)(Xb + i) = o;
    } else if (blk < 5120) {
        int l = blk - 4096;
        transpose_tile(w_q, Wqkv, C_DIM, C_DIM, (l & 31) * 32, (l >> 5) * 32, tid);
    } else if (blk < 5376) {
        int l = blk - 5120;
        transpose_tile(w_k, Wqkv + (size_t)1024 * C_DIM, C_DIM, 256,
                       (l & 7) * 32, (l >> 3) * 32, tid);
    } else if (blk < 5632) {
        int l = blk - 5376;
        transpose_tile(w_v, Wqkv + (size_t)1280 * C_DIM, C_DIM, 256,
                       (l & 7) * 32, (l >> 3) * 32, tid);
    } else if (blk < 6656) {
        int l = blk - 5632;
        transpose_tile(w_o, Wto, C_DIM, C_DIM, (l & 31) * 32, (l >> 5) * 32, tid);
    } else {
        int i = (blk - 6656) * 256 + tid;
        float v;
        if (i < 1024)      v = b_q[i];
        else if (i < 1280) v = b_k[i - 1024];
        else               v = b_v[i - 1280];
        Bqkv[i] = v;
    }
}

// ---------------------------------------------------------------------------
// MFMA GEMM (B^T input): C[M][N] = A[M][K] @ Bt[N][K]^T + bias. (round-5 core)
// ---------------------------------------------------------------------------
template <typename CT>
__global__ __launch_bounds__(256) void gemm_mfma_bt(
    const short* __restrict__ A, const short* __restrict__ Bt,
    const float* __restrict__ bias, CT* __restrict__ C,
    int M, int N, int K)
{
    __shared__ short sA[128][40];
    __shared__ short sB[128][40];

    int m0 = blockIdx.y * 128;
    int n0 = blockIdx.x * 128;
    int tid  = threadIdx.x;
    int w    = tid >> 6, lane = tid & 63;
    int quad = lane >> 4, l16 = lane & 15;
    int wm = w & 1, wn = w >> 1;

    f32x4 acc[4][4] = {};

    for (int k0 = 0; k0 < K; k0 += 32) {
        #pragma unroll
        for (int it = 0; it < 2; ++it) {
            int slot = tid + 256 * it;
            int row = slot >> 2, g = slot & 3;
            *(short8_t*)&sA[row][g * 8] =
                *(const short8_t*)(A + (size_t)(m0 + row) * K + k0 + g * 8);
        }
        #pragma unroll
        for (int it = 0; it < 2; ++it) {
            int slot = tid + 256 * it;
            int row = slot >> 2, g = slot & 3;
            *(short8_t*)&sB[row][g * 8] =
                *(const short8_t*)(Bt + (size_t)(n0 + row) * K + k0 + g * 8);
        }
        __syncthreads();

        short8_t af[4], bf[4];
        #pragma unroll
        for (int mt = 0; mt < 4; ++mt)
            af[mt] = *(const short8_t*)&sA[wm * 64 + mt * 16 + l16][quad * 8];
        #pragma unroll
        for (int nt = 0; nt < 4; ++nt)
            bf[nt] = *(const short8_t*)&sB[wn * 64 + nt * 16 + l16][quad * 8];
        #pragma unroll
        for (int mt = 0; mt < 4; ++mt)
            #pragma unroll
            for (int nt = 0; nt < 4; ++nt)
                acc[mt][nt] = __builtin_amdgcn_mfma_f32_16x16x32_bf16(
                    af[mt], bf[nt], acc[mt][nt], 0, 0, 0);
        __syncthreads();
    }

    #pragma unroll
    for (int mt = 0; mt < 4; ++mt) {
        #pragma unroll
        for (int nt = 0; nt < 4; ++nt) {
            int col = n0 + wn * 64 + nt * 16 + l16;
            float bv = bias[col];
            #pragma unroll
            for (int r = 0; r < 4; ++r) {
                int row = m0 + wm * 64 + mt * 16 + quad * 4 + r;
                store_c(&C[(size_t)row * N + col], acc[mt][nt][r] + bv);
            }
        }
    }
}

// ---------------------------------------------------------------------------
// RoPE over the fused QKV buffer: cols [0,1024) = Q heads, [1024,1280) = K
// heads — one contiguous range of 640 pairs per row. Q additionally
// pre-scaled by 1/sqrt(64)=0.125 (exact in bf16), so attention skips it.
// grid (3, 4096) x 256; pc guard at 640.
// ---------------------------------------------------------------------------
__global__ __launch_bounds__(256) void rope_qk_kernel(short* __restrict__ QKV)
{
    int pc = blockIdx.x * 256 + threadIdx.x;
    if (pc >= 640) return;
    int row = blockIdx.y;
    int col = pc * 2;
    int t = row & (T_SEQ - 1);
    int i = (col & 63) >> 1;
    float scale = (col < 1024) ? 0.125f : 1.0f;

    size_t base = (size_t)row * QKVW + col;
    float e = bs2f(QKV[base]);
    float o = bs2f(QKV[base + 1]);

    float freq = powf(10000.0f, -(float)(2 * i) / 64.0f);
    float ang  = (float)t * freq;
    float cs = cosf(ang);
    float sn = sinf(ang);

    QKV[base]     = f2bs((e * cs - o * sn) * scale);
    QKV[base + 1] = f2bs((e * sn + o * cs) * scale);
}

// ---------------------------------------------------------------------------
// MFMA flash attention v3.
//   Block = one 16-row q-tile of one (b,kvh); 4 waves = the 4 GQA heads
//   sharing kv head kvh (K/V staged once per chunk). Grid = 1024 blocks
//   (4 blocks/CU), long tiles dispatched first. Q pre-scaled by 0.125.
//   Register prefetch of next chunk; DPP max; MFMA row-sum; truncating
//   bf16 pack for P; rescale skipped when no row max changed.
// ---------------------------------------------------------------------------
__global__ __launch_bounds__(256) void attn_mfma3(
    const short* __restrict__ QKV, short* __restrict__ O)
{
    __shared__ short sK [64][72];
    __shared__ short sVt[64][72];
    __shared__ short sP [4][16][72];

    const int tid  = threadIdx.x;
    const int w    = tid >> 6;
    const int lane = tid & 63;
    const int quad = lane >> 4;
    const int l16  = lane & 15;

    int blk = blockIdx.x;
    int grp = blk & 7;                 // (b,kvh)
    int tq  = 127 - (blk >> 3);        // long tiles first
    int kvh = grp & 3;
    int b   = grp >> 2;
    int h   = kvh * 4 + w;
    int ct  = tq >> 2;                 // last chunk index

    const short* qptr = QKV + ((size_t)(b * T_SEQ + tq * 16 + l16)) * QKVW + h * HD;
    short8_t qf0 = *(const short8_t*)(qptr + quad * 8);
    short8_t qf1 = *(const short8_t*)(qptr + quad * 8 + 32);

    const short* kbase = QKV + (size_t)b * T_SEQ * QKVW + 1024 + kvh * HD;
    const short* vbase = QKV + (size_t)b * T_SEQ * QKVW + 1280 + kvh * HD;

    short8_t ones;
    #pragma unroll
    for (int i = 0; i < 8; ++i) ones[i] = (short)0x3F80;

    float mrow[4], lrow[4];
    f32x4 oacc[4];
    #pragma unroll
    for (int r = 0; r < 4; ++r) { mrow[r] = -INFINITY; lrow[r] = 0.f; }
    #pragma unroll
    for (int dt = 0; dt < 4; ++dt) oacc[dt] = (f32x4){0.f, 0.f, 0.f, 0.f};

    const int kkey = tid >> 3, kd = (tid & 7) * 8;
    const int vkey = tid & 63, vd = (tid >> 6) * 8;

    short8_t kr[2], vr[2];
    #pragma unroll
    for (int it = 0; it < 2; ++it) {
        kr[it] = *(const short8_t*)(kbase + (size_t)(kkey + 32 * it) * QKVW + kd);
        vr[it] = *(const short8_t*)(vbase + (size_t)vkey * QKVW + vd + 32 * it);
    }

    for (int c = 0; c <= ct; ++c) {
        __syncthreads();
        #pragma unroll
        for (int it = 0; it < 2; ++it) {
            *(short8_t*)&sK[kkey + 32 * it][kd] = kr[it];
            #pragma unroll
            for (int i = 0; i < 8; ++i) sVt[vd + 32 * it + i][vkey] = vr[it][i];
        }
        __syncthreads();
        if (c < ct) {
            int j0 = (c + 1) * 64;
            #pragma unroll
            for (int it = 0; it < 2; ++it) {
                kr[it] = *(const short8_t*)(kbase + (size_t)(j0 + kkey + 32 * it) * QKVW + kd);
                vr[it] = *(const short8_t*)(vbase + (size_t)(j0 + vkey) * QKVW + vd + 32 * it);
            }
        }

        // S = Q K^T (Q pre-scaled)
        f32x4 sacc[4];
        #pragma unroll
        for (int nt = 0; nt < 4; ++nt) {
            f32x4 z = {0.f, 0.f, 0.f, 0.f};
            short8_t kf0 = *(const short8_t*)&sK[l16 + 16 * nt][quad * 8];
            short8_t kf1 = *(const short8_t*)&sK[l16 + 16 * nt][quad * 8 + 32];
            z = __builtin_amdgcn_mfma_f32_16x16x32_bf16(qf0, kf0, z, 0, 0, 0);
            z = __builtin_amdgcn_mfma_f32_16x16x32_bf16(qf1, kf1, z, 0, 0, 0);
            sacc[nt] = z;
        }

        bool maskc = (c == ct);
        int j0 = c * 64;
        float al[4];
        #pragma unroll
        for (int r = 0; r < 4; ++r) {
            int trow = tq * 16 + quad * 4 + r;
            float sv[4], vmax = -INFINITY;
            #pragma unroll
            for (int nt = 0; nt < 4; ++nt) {
                float s = sacc[nt][r];
                if (maskc && (j0 + 16 * nt + l16 > trow)) s = -INFINITY;
                sv[nt] = s;
                vmax = fmaxf(vmax, s);
            }
            vmax = dpp_max16(vmax);
            float mnew = fmaxf(mrow[r], vmax);
            al[r] = __expf(mrow[r] - mnew);
            mrow[r] = mnew;
            #pragma unroll
            for (int nt = 0; nt < 4; ++nt)
                sP[w][quad * 4 + r][16 * nt + l16] = f2bs_trunc(__expf(sv[nt] - mnew));
        }
        if (__any((al[0] < 1.f) || (al[1] < 1.f) || (al[2] < 1.f) || (al[3] < 1.f))) {
            #pragma unroll
            for (int r = 0; r < 4; ++r) lrow[r] *= al[r];
            #pragma unroll
            for (int dt = 0; dt < 4; ++dt) {
                f32x4 o = oacc[dt];
                o[0] *= al[0]; o[1] *= al[1]; o[2] *= al[2]; o[3] *= al[3];
                oacc[dt] = o;
            }
        }

        short8_t pf0 = *(const short8_t*)&sP[w][l16][quad * 8];
        short8_t pf1 = *(const short8_t*)&sP[w][l16][quad * 8 + 32];
        f32x4 rs = {0.f, 0.f, 0.f, 0.f};
        rs = __builtin_amdgcn_mfma_f32_16x16x32_bf16(pf0, ones, rs, 0, 0, 0);
        rs = __builtin_amdgcn_mfma_f32_16x16x32_bf16(pf1, ones, rs, 0, 0, 0);
        #pragma unroll
        for (int r = 0; r < 4; ++r) lrow[r] += rs[r];
        #pragma unroll
        for (int dt = 0; dt < 4; ++dt) {
            short8_t vf0 = *(const short8_t*)&sVt[l16 + 16 * dt][quad * 8];
            short8_t vf1 = *(const short8_t*)&sVt[l16 + 16 * dt][quad * 8 + 32];
            oacc[dt] = __builtin_amdgcn_mfma_f32_16x16x32_bf16(pf0, vf0, oacc[dt], 0, 0, 0);
            oacc[dt] = __builtin_amdgcn_mfma_f32_16x16x32_bf16(pf1, vf1, oacc[dt], 0, 0, 0);
        }
    }

    #pragma unroll
    for (int r = 0; r < 4; ++r) {
        int m = quad * 4 + r;
        float inv = __builtin_amdgcn_rcpf(lrow[r]);
        #pragma unroll
        for (int dt = 0; dt < 4; ++dt)
            O[((size_t)b * T_SEQ + tq * 16 + m) * C_DIM + h * HD + 16 * dt + l16] =
                f2bs(oacc[dt][r] * inv);
    }
}

// ---------------------------------------------------------------------------
extern "C" void kernel_launch(void* const* d_in, const int* in_sizes, int n_in,
                              void* d_out, int out_size, void* d_ws, size_t ws_size,
                              hipStream_t stream)
{
    const float* x   = (const float*)d_in[0];
    const float* w_q = (const float*)d_in[1];
    const float* b_q = (const float*)d_in[2];
    const float* w_k = (const float*)d_in[3];
    const float* b_k = (const float*)d_in[4];
    const float* w_v = (const float*)d_in[5];
    const float* b_v = (const float*)d_in[6];
    const float* w_o = (const float*)d_in[7];
    const float* b_o = (const float*)d_in[8];
    float* out = (float*)d_out;

    char* ws = (char*)d_ws;
    short* Xb   = (short*)(ws);                          // 8 MB   [0,8M)
    short* Ab   = (short*)(ws + ((size_t)8  << 20));     // 8 MB   [8M,16M)
    short* QKVb = (short*)(ws + ((size_t)16 << 20));     // 12 MB  [16M,28M)
    short* Wqkv = (short*)(ws + ((size_t)28 << 20));     // 3 MB   [28M,31M)
    short* Wto  = (short*)(ws + ((size_t)31 << 20));     // 2 MB   [31M,33M)
    float* Bqkv = (float*)(ws + ((size_t)33 << 20));     // 6 KB   [33M,..)

    const int M = B_SZ * T_SEQ;   // 4096

    prep_kernel<<<6662, 256, 0, stream>>>(
        x, w_q, w_k, w_v, w_o, b_q, b_k, b_v, Xb, Wqkv, Wto, Bqkv);

    gemm_mfma_bt<short><<<dim3(QKVW / 128, M / 128), 256, 0, stream>>>(
        Xb, Wqkv, Bqkv, QKVb, M, QKVW, C_DIM);

    rope_qk_kernel<<<dim3(3, M), 256, 0, stream>>>(QKVb);

    attn_mfma3<<<B_SZ * NKV * 128, 256, 0, stream>>>(QKVb, Ab);

    gemm_mfma_bt<float><<<dim3(C_DIM / 128, M / 128), 256, 0, stream>>>(
        Ab, Wto, b_o, out, M, C_DIM, C_DIM);
}

// Round 8
// 190.543 us; speedup vs baseline: 14.2181x; 1.0854x over previous
//
#include <hip/hip_runtime.h>
#include <hip/hip_bf16.h>

typedef __hip_bfloat16 bf16;
typedef __attribute__((ext_vector_type(8))) short short8_t;
typedef __attribute__((ext_vector_type(4))) short short4_t;
typedef __attribute__((ext_vector_type(4))) float f32x4;

#define B_SZ   2
#define T_SEQ  2048
#define C_DIM  1024
#define NH     16
#define NKV    4
#define HD     64
#define QKVW   1536          // fused QKV row width (1024 Q | 256 K | 256 V)

// log2(10000)/32 — inv_freq_i = 2^(-i * this)
#define LOG2_BASE_OVER_32 0.4152410118609203f
// 0.125 * log2(e): folds softmax scale + exp->exp2 domain change into Q
#define Q_SCALE 0.1803368801111204f

// float -> bf16 bits (round-nearest-even)
__device__ __forceinline__ short f2bs(float f) {
    unsigned u = __float_as_uint(f);
    u += 0x7FFFu + ((u >> 16) & 1u);
    return (short)(u >> 16);
}
// float -> bf16 bits (truncate) — for P tiles, consistent num/denom
__device__ __forceinline__ short f2bs_trunc(float f) {
    return (short)(__float_as_uint(f) >> 16);
}
__device__ __forceinline__ float bs2f(short s) {
    unsigned u = ((unsigned)(unsigned short)s) << 16;
    return __uint_as_float(u);
}

__device__ __forceinline__ void store_c(float* p, float v) { *p = v; }
__device__ __forceinline__ void store_c(short* p, float v) { *p = f2bs(v); }

// max over each 16-lane row via DPP — pure VALU
__device__ __forceinline__ float dpp_max16(float x) {
    int t;
    t = __builtin_amdgcn_update_dpp(0, __float_as_int(x), 0xB1, 0xF, 0xF, true);  // quad_perm [1,0,3,2]
    x = fmaxf(x, __int_as_float(t));
    t = __builtin_amdgcn_update_dpp(0, __float_as_int(x), 0x4E, 0xF, 0xF, true);  // quad_perm [2,3,0,1]
    x = fmaxf(x, __int_as_float(t));
    t = __builtin_amdgcn_update_dpp(0, __float_as_int(x), 0x141, 0xF, 0xF, true); // row_half_mirror
    x = fmaxf(x, __int_as_float(t));
    t = __builtin_amdgcn_update_dpp(0, __float_as_int(x), 0x140, 0xF, 0xF, true); // row_mirror
    x = fmaxf(x, __int_as_float(t));
    return x;
}

// ---------------------------------------------------------------------------
// Fused prep (unchanged from round 7)
// ---------------------------------------------------------------------------
__device__ __forceinline__ void transpose_tile(
    const float* __restrict__ W, short* __restrict__ Wt,
    int K, int N, int n0, int k0, int tid)
{
    __shared__ float tile[32][33];
    int tx = tid & 31, ty = tid >> 5;   // (32,8)
    #pragma unroll
    for (int i = 0; i < 4; ++i)
        tile[ty + 8 * i][tx] = W[(size_t)(k0 + ty + 8 * i) * N + n0 + tx];
    __syncthreads();
    #pragma unroll
    for (int i = 0; i < 4; ++i)
        Wt[(size_t)(n0 + ty + 8 * i) * K + k0 + tx] = f2bs(tile[tx][ty + 8 * i]);
}

__global__ __launch_bounds__(256) void prep_kernel(
    const float* __restrict__ x,
    const float* __restrict__ w_q, const float* __restrict__ w_k,
    const float* __restrict__ w_v, const float* __restrict__ w_o,
    const float* __restrict__ b_q, const float* __restrict__ b_k,
    const float* __restrict__ b_v,
    short* __restrict__ Xb, short* __restrict__ Wqkv, short* __restrict__ Wto,
    float* __restrict__ Bqkv)
{
    int blk = blockIdx.x, tid = threadIdx.x;
    if (blk < 4096) {
        int i = blk * 1024 + tid * 4;
        float4 v = *(const float4*)(x + i);
        short4_t o;
        o[0] = f2bs(v.x); o[1] = f2bs(v.y); o[2] = f2bs(v.z); o[3] = f2bs(v.w);
        *(short4_t*)(Xb + i) = o;
    } else if (blk < 5120) {
        int l = blk - 4096;
        transpose_tile(w_q, Wqkv, C_DIM, C_DIM, (l & 31) * 32, (l >> 5) * 32, tid);
    } else if (blk < 5376) {
        int l = blk - 5120;
        transpose_tile(w_k, Wqkv + (size_t)1024 * C_DIM, C_DIM, 256,
                       (l & 7) * 32, (l >> 3) * 32, tid);
    } else if (blk < 5632) {
        int l = blk - 5376;
        transpose_tile(w_v, Wqkv + (size_t)1280 * C_DIM, C_DIM, 256,
                       (l & 7) * 32, (l >> 3) * 32, tid);
    } else if (blk < 6656) {
        int l = blk - 5632;
        transpose_tile(w_o, Wto, C_DIM, C_DIM, (l & 31) * 32, (l >> 5) * 32, tid);
    } else {
        int i = (blk - 6656) * 256 + tid;
        float v;
        if (i < 1024)      v = b_q[i];
        else if (i < 1280) v = b_k[i - 1024];
        else               v = b_v[i - 1280];
        Bqkv[i] = v;
    }
}

// ---------------------------------------------------------------------------
// MFMA GEMM (B^T input) with double-buffered LDS: one barrier per k-iter,
// register prefetch of next k-tile overlapped with MFMA compute.
// ---------------------------------------------------------------------------
template <typename CT>
__global__ __launch_bounds__(256) void gemm_mfma_bt(
    const short* __restrict__ A, const short* __restrict__ Bt,
    const float* __restrict__ bias, CT* __restrict__ C,
    int M, int N, int K)
{
    __shared__ __align__(16) short sA[2][128][40];
    __shared__ __align__(16) short sB[2][128][40];

    int m0 = blockIdx.y * 128;
    int n0 = blockIdx.x * 128;
    int tid  = threadIdx.x;
    int w    = tid >> 6, lane = tid & 63;
    int quad = lane >> 4, l16 = lane & 15;
    int wm = w & 1, wn = w >> 1;

    f32x4 acc[4][4] = {};

    short8_t ra[2], rb[2];
    #pragma unroll
    for (int it = 0; it < 2; ++it) {
        int slot = tid + 256 * it, row = slot >> 2, g = (slot & 3) * 8;
        ra[it] = *(const short8_t*)(A  + (size_t)(m0 + row) * K + g);
        rb[it] = *(const short8_t*)(Bt + (size_t)(n0 + row) * K + g);
    }

    int buf = 0;
    for (int k0 = 0; k0 < K; k0 += 32, buf ^= 1) {
        #pragma unroll
        for (int it = 0; it < 2; ++it) {
            int slot = tid + 256 * it, row = slot >> 2, g = (slot & 3) * 8;
            *(short8_t*)&sA[buf][row][g] = ra[it];
            *(short8_t*)&sB[buf][row][g] = rb[it];
        }
        if (k0 + 32 < K) {
            #pragma unroll
            for (int it = 0; it < 2; ++it) {
                int slot = tid + 256 * it, row = slot >> 2, g = (slot & 3) * 8;
                ra[it] = *(const short8_t*)(A  + (size_t)(m0 + row) * K + k0 + 32 + g);
                rb[it] = *(const short8_t*)(Bt + (size_t)(n0 + row) * K + k0 + 32 + g);
            }
        }
        __syncthreads();

        short8_t af[4], bfr[4];
        #pragma unroll
        for (int mt = 0; mt < 4; ++mt)
            af[mt] = *(const short8_t*)&sA[buf][wm * 64 + mt * 16 + l16][quad * 8];
        #pragma unroll
        for (int nt = 0; nt < 4; ++nt)
            bfr[nt] = *(const short8_t*)&sB[buf][wn * 64 + nt * 16 + l16][quad * 8];
        #pragma unroll
        for (int mt = 0; mt < 4; ++mt)
            #pragma unroll
            for (int nt = 0; nt < 4; ++nt)
                acc[mt][nt] = __builtin_amdgcn_mfma_f32_16x16x32_bf16(
                    af[mt], bfr[nt], acc[mt][nt], 0, 0, 0);
    }

    #pragma unroll
    for (int mt = 0; mt < 4; ++mt) {
        #pragma unroll
        for (int nt = 0; nt < 4; ++nt) {
            int col = n0 + wn * 64 + nt * 16 + l16;
            float bv = bias[col];
            #pragma unroll
            for (int r = 0; r < 4; ++r) {
                int row = m0 + wm * 64 + mt * 16 + quad * 4 + r;
                store_c(&C[(size_t)row * N + col], acc[mt][nt][r] + bv);
            }
        }
    }
}

// ---------------------------------------------------------------------------
// RoPE on K only (Q is roped inside attention now). Cols [1024,1280).
// ---------------------------------------------------------------------------
__global__ __launch_bounds__(256) void rope_k_kernel(short* __restrict__ QKV)
{
    int g = blockIdx.x * 256 + threadIdx.x;       // 4096 rows x 128 pairs
    int row = g >> 7, pi = g & 127;
    int col = 1024 + pi * 2;
    int t = row & (T_SEQ - 1);
    int i = pi & 31;

    size_t base = (size_t)row * QKVW + col;
    float e = bs2f(QKV[base]);
    float o = bs2f(QKV[base + 1]);

    float fr  = exp2f(-(float)i * LOG2_BASE_OVER_32);
    float ang = (float)t * fr;
    float sn = sinf(ang), cs = cosf(ang);

    QKV[base]     = f2bs(e * cs - o * sn);
    QKV[base + 1] = f2bs(e * sn + o * cs);
}

// ---------------------------------------------------------------------------
// MFMA flash attention v4.
//   Block = one 16-row q-tile of one (b,kvh); 4 waves = 4 GQA heads sharing
//   staged K/V. Double-buffered K/V LDS -> ONE barrier per chunk; register
//   prefetch of chunk c+1 spans the whole compute of chunk c.
//   Q roped + scaled by 0.125*log2e on load (exp2-domain softmax).
// ---------------------------------------------------------------------------
__global__ __launch_bounds__(256) void attn_mfma4(
    const short* __restrict__ QKV, short* __restrict__ O)
{
    __shared__ __align__(16) short sK [2][64][72];
    __shared__ __align__(16) short sVt[2][64][72];
    __shared__ __align__(16) short sP [4][16][72];

    const int tid  = threadIdx.x;
    const int w    = tid >> 6;
    const int lane = tid & 63;
    const int quad = lane >> 4;
    const int l16  = lane & 15;

    int blk = blockIdx.x;
    int grp = blk & 7;                 // (b,kvh)
    int tq  = 127 - (blk >> 3);        // long tiles first
    int kvh = grp & 3;
    int b   = grp >> 2;
    int h   = kvh * 4 + w;
    int ct  = tq >> 2;                 // last chunk index

    // ---- load Q frags, apply RoPE (interleaved) + 0.125*log2e scale
    const short* qptr = QKV + ((size_t)(b * T_SEQ + tq * 16 + l16)) * QKVW + h * HD;
    short8_t q0r = *(const short8_t*)(qptr + quad * 8);
    short8_t q1r = *(const short8_t*)(qptr + quad * 8 + 32);
    int t = tq * 16 + l16;
    short8_t qf0, qf1;
    #pragma unroll
    for (int j = 0; j < 4; ++j) {
        int i0 = quad * 4 + j;
        float a0 = (float)t * exp2f(-(float)i0 * LOG2_BASE_OVER_32);
        float s0 = sinf(a0), c0 = cosf(a0);
        float e0 = bs2f(q0r[2 * j]), o0 = bs2f(q0r[2 * j + 1]);
        qf0[2 * j]     = f2bs((e0 * c0 - o0 * s0) * Q_SCALE);
        qf0[2 * j + 1] = f2bs((e0 * s0 + o0 * c0) * Q_SCALE);
        int i1 = i0 + 16;
        float a1 = (float)t * exp2f(-(float)i1 * LOG2_BASE_OVER_32);
        float s1 = sinf(a1), c1 = cosf(a1);
        float e1 = bs2f(q1r[2 * j]), o1 = bs2f(q1r[2 * j + 1]);
        qf1[2 * j]     = f2bs((e1 * c1 - o1 * s1) * Q_SCALE);
        qf1[2 * j + 1] = f2bs((e1 * s1 + o1 * c1) * Q_SCALE);
    }

    const short* kbase = QKV + (size_t)b * T_SEQ * QKVW + 1024 + kvh * HD;
    const short* vbase = QKV + (size_t)b * T_SEQ * QKVW + 1280 + kvh * HD;

    short8_t ones;
    #pragma unroll
    for (int i = 0; i < 8; ++i) ones[i] = (short)0x3F80;

    float mrow[4], lrow[4];
    f32x4 oacc[4];
    #pragma unroll
    for (int r = 0; r < 4; ++r) { mrow[r] = -INFINITY; lrow[r] = 0.f; }
    #pragma unroll
    for (int dt = 0; dt < 4; ++dt) oacc[dt] = (f32x4){0.f, 0.f, 0.f, 0.f};

    const int kkey = tid >> 3, kd = (tid & 7) * 8;
    const int vkey = tid & 63, vd = (tid >> 6) * 8;

    short8_t kr[2], vr[2];
    #pragma unroll
    for (int it = 0; it < 2; ++it) {
        kr[it] = *(const short8_t*)(kbase + (size_t)(kkey + 32 * it) * QKVW + kd);
        vr[it] = *(const short8_t*)(vbase + (size_t)vkey * QKVW + vd + 32 * it);
    }

    for (int c = 0; c <= ct; ++c) {
        int buf = c & 1;
        // write staged chunk c into LDS buffer `buf`
        #pragma unroll
        for (int it = 0; it < 2; ++it) {
            *(short8_t*)&sK[buf][kkey + 32 * it][kd] = kr[it];
            #pragma unroll
            for (int i = 0; i < 8; ++i) sVt[buf][vd + 32 * it + i][vkey] = vr[it][i];
        }
        // prefetch chunk c+1 into registers (hidden under barrier+compute)
        if (c < ct) {
            int jn = (c + 1) * 64;
            #pragma unroll
            for (int it = 0; it < 2; ++it) {
                kr[it] = *(const short8_t*)(kbase + (size_t)(jn + kkey + 32 * it) * QKVW + kd);
                vr[it] = *(const short8_t*)(vbase + (size_t)(jn + vkey) * QKVW + vd + 32 * it);
            }
        }
        __syncthreads();

        // S = Q K^T (log2-domain, pre-scaled)
        f32x4 sacc[4];
        #pragma unroll
        for (int nt = 0; nt < 4; ++nt) {
            f32x4 z = {0.f, 0.f, 0.f, 0.f};
            short8_t kf0 = *(const short8_t*)&sK[buf][l16 + 16 * nt][quad * 8];
            short8_t kf1 = *(const short8_t*)&sK[buf][l16 + 16 * nt][quad * 8 + 32];
            z = __builtin_amdgcn_mfma_f32_16x16x32_bf16(qf0, kf0, z, 0, 0, 0);
            z = __builtin_amdgcn_mfma_f32_16x16x32_bf16(qf1, kf1, z, 0, 0, 0);
            sacc[nt] = z;
        }

        bool maskc = (c == ct);
        int j0 = c * 64;
        float al[4];
        #pragma unroll
        for (int r = 0; r < 4; ++r) {
            int trow = tq * 16 + quad * 4 + r;
            float sv[4], vmax = -INFINITY;
            #pragma unroll
            for (int nt = 0; nt < 4; ++nt) {
                float s = sacc[nt][r];
                if (maskc && (j0 + 16 * nt + l16 > trow)) s = -INFINITY;
                sv[nt] = s;
                vmax = fmaxf(vmax, s);
            }
            vmax = dpp_max16(vmax);
            float mnew = fmaxf(mrow[r], vmax);
            al[r] = exp2f(mrow[r] - mnew);
            mrow[r] = mnew;
            #pragma unroll
            for (int nt = 0; nt < 4; ++nt)
                sP[w][quad * 4 + r][16 * nt + l16] = f2bs_trunc(exp2f(sv[nt] - mnew));
        }
        if (__any((al[0] < 1.f) || (al[1] < 1.f) || (al[2] < 1.f) || (al[3] < 1.f))) {
            #pragma unroll
            for (int r = 0; r < 4; ++r) lrow[r] *= al[r];
            #pragma unroll
            for (int dt = 0; dt < 4; ++dt) {
                f32x4 o = oacc[dt];
                o[0] *= al[0]; o[1] *= al[1]; o[2] *= al[2]; o[3] *= al[3];
                oacc[dt] = o;
            }
        }

        short8_t pf0 = *(const short8_t*)&sP[w][l16][quad * 8];
        short8_t pf1 = *(const short8_t*)&sP[w][l16][quad * 8 + 32];
        f32x4 rs = {0.f, 0.f, 0.f, 0.f};
        rs = __builtin_amdgcn_mfma_f32_16x16x32_bf16(pf0, ones, rs, 0, 0, 0);
        rs = __builtin_amdgcn_mfma_f32_16x16x32_bf16(pf1, ones, rs, 0, 0, 0);
        #pragma unroll
        for (int r = 0; r < 4; ++r) lrow[r] += rs[r];
        #pragma unroll
        for (int dt = 0; dt < 4; ++dt) {
            short8_t vf0 = *(const short8_t*)&sVt[buf][l16 + 16 * dt][quad * 8];
            short8_t vf1 = *(const short8_t*)&sVt[buf][l16 + 16 * dt][quad * 8 + 32];
            oacc[dt] = __builtin_amdgcn_mfma_f32_16x16x32_bf16(pf0, vf0, oacc[dt], 0, 0, 0);
            oacc[dt] = __builtin_amdgcn_mfma_f32_16x16x32_bf16(pf1, vf1, oacc[dt], 0, 0, 0);
        }
    }

    #pragma unroll
    for (int r = 0; r < 4; ++r) {
        int m = quad * 4 + r;
        float inv = __builtin_amdgcn_rcpf(lrow[r]);
        #pragma unroll
        for (int dt = 0; dt < 4; ++dt)
            O[((size_t)b * T_SEQ + tq * 16 + m) * C_DIM + h * HD + 16 * dt + l16] =
                f2bs(oacc[dt][r] * inv);
    }
}

// ---------------------------------------------------------------------------
extern "C" void kernel_launch(void* const* d_in, const int* in_sizes, int n_in,
                              void* d_out, int out_size, void* d_ws, size_t ws_size,
                              hipStream_t stream)
{
    const float* x   = (const float*)d_in[0];
    const float* w_q = (const float*)d_in[1];
    const float* b_q = (const float*)d_in[2];
    const float* w_k = (const float*)d_in[3];
    const float* b_k = (const float*)d_in[4];
    const float* w_v = (const float*)d_in[5];
    const float* b_v = (const float*)d_in[6];
    const float* w_o = (const float*)d_in[7];
    const float* b_o = (const float*)d_in[8];
    float* out = (float*)d_out;

    char* ws = (char*)d_ws;
    short* Xb   = (short*)(ws);                          // 8 MB
    short* Ab   = (short*)(ws + ((size_t)8  << 20));     // 8 MB
    short* QKVb = (short*)(ws + ((size_t)16 << 20));     // 12 MB
    short* Wqkv = (short*)(ws + ((size_t)28 << 20));     // 3 MB
    short* Wto  = (short*)(ws + ((size_t)31 << 20));     // 2 MB
    float* Bqkv = (float*)(ws + ((size_t)33 << 20));     // 6 KB

    const int M = B_SZ * T_SEQ;   // 4096

    prep_kernel<<<6662, 256, 0, stream>>>(
        x, w_q, w_k, w_v, w_o, b_q, b_k, b_v, Xb, Wqkv, Wto, Bqkv);

    gemm_mfma_bt<short><<<dim3(QKVW / 128, M / 128), 256, 0, stream>>>(
        Xb, Wqkv, Bqkv, QKVb, M, QKVW, C_DIM);

    rope_k_kernel<<<2048, 256, 0, stream>>>(QKVb);

    attn_mfma4<<<B_SZ * NKV * 128, 256, 0, stream>>>(QKVb, Ab);

    gemm_mfma_bt<float><<<dim3(C_DIM / 128, M / 128), 256, 0, stream>>>(
        Ab, Wto, b_o, out, M, C_DIM, C_DIM);
}

// Round 9
// 190.265 us; speedup vs baseline: 14.2388x; 1.0015x over previous
//
#include <hip/hip_runtime.h>
#include <hip/hip_bf16.h>

typedef __hip_bfloat16 bf16;
typedef __attribute__((ext_vector_type(8))) short short8_t;
typedef __attribute__((ext_vector_type(4))) short short4_t;
typedef __attribute__((ext_vector_type(4))) float f32x4;

#define B_SZ   2
#define T_SEQ  2048
#define C_DIM  1024
#define NH     16
#define NKV    4
#define HD     64
#define QKVW   1536          // fused QKV row width (1024 Q | 256 K | 256 V)

// log2(10000)/32 — inv_freq_i = 2^(-i * this)
#define LOG2_BASE_OVER_32 0.4152410118609203f
// 0.125 * log2(e): folds softmax scale + exp->exp2 domain change into Q
#define Q_SCALE 0.1803368801111204f

// float -> bf16 bits (round-nearest-even)
__device__ __forceinline__ short f2bs(float f) {
    unsigned u = __float_as_uint(f);
    u += 0x7FFFu + ((u >> 16) & 1u);
    return (short)(u >> 16);
}
// float -> bf16 bits (truncate) — for P tiles, consistent num/denom
__device__ __forceinline__ short f2bs_trunc(float f) {
    return (short)(__float_as_uint(f) >> 16);
}
__device__ __forceinline__ float bs2f(short s) {
    unsigned u = ((unsigned)(unsigned short)s) << 16;
    return __uint_as_float(u);
}

__device__ __forceinline__ void store_c(float* p, float v) { *p = v; }
__device__ __forceinline__ void store_c(short* p, float v) { *p = f2bs(v); }

// max over each 16-lane row via DPP — pure VALU
__device__ __forceinline__ float dpp_max16(float x) {
    int t;
    t = __builtin_amdgcn_update_dpp(0, __float_as_int(x), 0xB1, 0xF, 0xF, true);  // quad_perm [1,0,3,2]
    x = fmaxf(x, __int_as_float(t));
    t = __builtin_amdgcn_update_dpp(0, __float_as_int(x), 0x4E, 0xF, 0xF, true);  // quad_perm [2,3,0,1]
    x = fmaxf(x, __int_as_float(t));
    t = __builtin_amdgcn_update_dpp(0, __float_as_int(x), 0x141, 0xF, 0xF, true); // row_half_mirror
    x = fmaxf(x, __int_as_float(t));
    t = __builtin_amdgcn_update_dpp(0, __float_as_int(x), 0x140, 0xF, 0xF, true); // row_mirror
    x = fmaxf(x, __int_as_float(t));
    return x;
}

// ---------------------------------------------------------------------------
// Fused prep: x->bf16, weight transposes, bias concat, AND the RoPE cos/sin
// table Tab[t][i] = (cos, sin)(t * 10000^(-i/32)), t<2048, i<32.
//   [0,4096) x | [4096,5120) w_q | [5120,5376) w_k | [5376,5632) w_v
//   [5632,6656) w_o | [6656,6662) bias | [6662,6918) table
// ---------------------------------------------------------------------------
__device__ __forceinline__ void transpose_tile(
    const float* __restrict__ W, short* __restrict__ Wt,
    int K, int N, int n0, int k0, int tid)
{
    __shared__ float tile[32][33];
    int tx = tid & 31, ty = tid >> 5;   // (32,8)
    #pragma unroll
    for (int i = 0; i < 4; ++i)
        tile[ty + 8 * i][tx] = W[(size_t)(k0 + ty + 8 * i) * N + n0 + tx];
    __syncthreads();
    #pragma unroll
    for (int i = 0; i < 4; ++i)
        Wt[(size_t)(n0 + ty + 8 * i) * K + k0 + tx] = f2bs(tile[tx][ty + 8 * i]);
}

__global__ __launch_bounds__(256) void prep_kernel(
    const float* __restrict__ x,
    const float* __restrict__ w_q, const float* __restrict__ w_k,
    const float* __restrict__ w_v, const float* __restrict__ w_o,
    const float* __restrict__ b_q, const float* __restrict__ b_k,
    const float* __restrict__ b_v,
    short* __restrict__ Xb, short* __restrict__ Wqkv, short* __restrict__ Wto,
    float* __restrict__ Bqkv, float2* __restrict__ Tab)
{
    int blk = blockIdx.x, tid = threadIdx.x;
    if (blk < 4096) {
        int i = blk * 1024 + tid * 4;
        float4 v = *(const float4*)(x + i);
        short4_t o;
        o[0] = f2bs(v.x); o[1] = f2bs(v.y); o[2] = f2bs(v.z); o[3] = f2bs(v.w);
        *(short4_t*)(Xb + i) = o;
    } else if (blk < 5120) {
        int l = blk - 4096;
        transpose_tile(w_q, Wqkv, C_DIM, C_DIM, (l & 31) * 32, (l >> 5) * 32, tid);
    } else if (blk < 5376) {
        int l = blk - 5120;
        transpose_tile(w_k, Wqkv + (size_t)1024 * C_DIM, C_DIM, 256,
                       (l & 7) * 32, (l >> 3) * 32, tid);
    } else if (blk < 5632) {
        int l = blk - 5376;
        transpose_tile(w_v, Wqkv + (size_t)1280 * C_DIM, C_DIM, 256,
                       (l & 7) * 32, (l >> 3) * 32, tid);
    } else if (blk < 6656) {
        int l = blk - 5632;
        transpose_tile(w_o, Wto, C_DIM, C_DIM, (l & 31) * 32, (l >> 5) * 32, tid);
    } else if (blk < 6662) {
        int i = (blk - 6656) * 256 + tid;
        float v;
        if (i < 1024)      v = b_q[i];
        else if (i < 1280) v = b_k[i - 1024];
        else               v = b_v[i - 1280];
        Bqkv[i] = v;
    } else {
        int idx = (blk - 6662) * 256 + tid;     // 65536 entries
        int t = idx >> 5, i = idx & 31;
        float ang = (float)t * exp2f(-(float)i * LOG2_BASE_OVER_32);
        Tab[idx] = make_float2(cosf(ang), sinf(ang));
    }
}

// ---------------------------------------------------------------------------
// MFMA GEMM (B^T input) with double-buffered LDS (round-8 version, works).
// ---------------------------------------------------------------------------
template <typename CT>
__global__ __launch_bounds__(256) void gemm_mfma_bt(
    const short* __restrict__ A, const short* __restrict__ Bt,
    const float* __restrict__ bias, CT* __restrict__ C,
    int M, int N, int K)
{
    __shared__ __align__(16) short sA[2][128][40];
    __shared__ __align__(16) short sB[2][128][40];

    int m0 = blockIdx.y * 128;
    int n0 = blockIdx.x * 128;
    int tid  = threadIdx.x;
    int w    = tid >> 6, lane = tid & 63;
    int quad = lane >> 4, l16 = lane & 15;
    int wm = w & 1, wn = w >> 1;

    f32x4 acc[4][4] = {};

    short8_t ra[2], rb[2];
    #pragma unroll
    for (int it = 0; it < 2; ++it) {
        int slot = tid + 256 * it, row = slot >> 2, g = (slot & 3) * 8;
        ra[it] = *(const short8_t*)(A  + (size_t)(m0 + row) * K + g);
        rb[it] = *(const short8_t*)(Bt + (size_t)(n0 + row) * K + g);
    }

    int buf = 0;
    for (int k0 = 0; k0 < K; k0 += 32, buf ^= 1) {
        #pragma unroll
        for (int it = 0; it < 2; ++it) {
            int slot = tid + 256 * it, row = slot >> 2, g = (slot & 3) * 8;
            *(short8_t*)&sA[buf][row][g] = ra[it];
            *(short8_t*)&sB[buf][row][g] = rb[it];
        }
        if (k0 + 32 < K) {
            #pragma unroll
            for (int it = 0; it < 2; ++it) {
                int slot = tid + 256 * it, row = slot >> 2, g = (slot & 3) * 8;
                ra[it] = *(const short8_t*)(A  + (size_t)(m0 + row) * K + k0 + 32 + g);
                rb[it] = *(const short8_t*)(Bt + (size_t)(n0 + row) * K + k0 + 32 + g);
            }
        }
        __syncthreads();

        short8_t af[4], bfr[4];
        #pragma unroll
        for (int mt = 0; mt < 4; ++mt)
            af[mt] = *(const short8_t*)&sA[buf][wm * 64 + mt * 16 + l16][quad * 8];
        #pragma unroll
        for (int nt = 0; nt < 4; ++nt)
            bfr[nt] = *(const short8_t*)&sB[buf][wn * 64 + nt * 16 + l16][quad * 8];
        #pragma unroll
        for (int mt = 0; mt < 4; ++mt)
            #pragma unroll
            for (int nt = 0; nt < 4; ++nt)
                acc[mt][nt] = __builtin_amdgcn_mfma_f32_16x16x32_bf16(
                    af[mt], bfr[nt], acc[mt][nt], 0, 0, 0);
    }

    #pragma unroll
    for (int mt = 0; mt < 4; ++mt) {
        #pragma unroll
        for (int nt = 0; nt < 4; ++nt) {
            int col = n0 + wn * 64 + nt * 16 + l16;
            float bv = bias[col];
            #pragma unroll
            for (int r = 0; r < 4; ++r) {
                int row = m0 + wm * 64 + mt * 16 + quad * 4 + r;
                store_c(&C[(size_t)row * N + col], acc[mt][nt][r] + bv);
            }
        }
    }
}

// ---------------------------------------------------------------------------
// RoPE on K (cols [1024,1280)) via the precomputed table — no transcendentals.
// ---------------------------------------------------------------------------
__global__ __launch_bounds__(256) void rope_k_kernel(
    short* __restrict__ QKV, const float2* __restrict__ Tab)
{
    int g = blockIdx.x * 256 + threadIdx.x;       // 4096 rows x 128 pairs
    int row = g >> 7, pi = g & 127;
    int col = 1024 + pi * 2;
    int t = row & (T_SEQ - 1);
    int i = pi & 31;

    size_t base = (size_t)row * QKVW + col;
    float e = bs2f(QKV[base]);
    float o = bs2f(QKV[base + 1]);

    float2 cs = Tab[t * 32 + i];

    QKV[base]     = f2bs(e * cs.x - o * cs.y);
    QKV[base + 1] = f2bs(e * cs.y + o * cs.x);
}

// ---------------------------------------------------------------------------
// MFMA flash attention v5 = v3 structure (single-buffer, 27.6 KB LDS,
// 4 blocks/CU) + exp2-domain softmax + table-based Q-RoPE in the prologue
// (Q_SCALE = 0.125*log2e folded in; no transcendentals in-kernel).
// ---------------------------------------------------------------------------
__global__ __launch_bounds__(256) void attn_mfma5(
    const short* __restrict__ QKV, const float2* __restrict__ Tab,
    short* __restrict__ O)
{
    __shared__ __align__(16) short sK [64][72];
    __shared__ __align__(16) short sVt[64][72];
    __shared__ __align__(16) short sP [4][16][72];

    const int tid  = threadIdx.x;
    const int w    = tid >> 6;
    const int lane = tid & 63;
    const int quad = lane >> 4;
    const int l16  = lane & 15;

    int blk = blockIdx.x;
    int grp = blk & 7;                 // (b,kvh)
    int tq  = 127 - (blk >> 3);        // long tiles first
    int kvh = grp & 3;
    int b   = grp >> 2;
    int h   = kvh * 4 + w;
    int ct  = tq >> 2;                 // last chunk index

    // ---- Q frags: load, rope via table, scale by Q_SCALE
    const short* qptr = QKV + ((size_t)(b * T_SEQ + tq * 16 + l16)) * QKVW + h * HD;
    short8_t q0r = *(const short8_t*)(qptr + quad * 8);
    short8_t q1r = *(const short8_t*)(qptr + quad * 8 + 32);
    int t = tq * 16 + l16;
    const float2* tb = Tab + t * 32 + quad * 4;
    short8_t qf0, qf1;
    #pragma unroll
    for (int j = 0; j < 4; ++j) {
        float2 cs0 = tb[j];
        float e0 = bs2f(q0r[2 * j]), o0 = bs2f(q0r[2 * j + 1]);
        qf0[2 * j]     = f2bs((e0 * cs0.x - o0 * cs0.y) * Q_SCALE);
        qf0[2 * j + 1] = f2bs((e0 * cs0.y + o0 * cs0.x) * Q_SCALE);
        float2 cs1 = tb[j + 16];
        float e1 = bs2f(q1r[2 * j]), o1 = bs2f(q1r[2 * j + 1]);
        qf1[2 * j]     = f2bs((e1 * cs1.x - o1 * cs1.y) * Q_SCALE);
        qf1[2 * j + 1] = f2bs((e1 * cs1.y + o1 * cs1.x) * Q_SCALE);
    }

    const short* kbase = QKV + (size_t)b * T_SEQ * QKVW + 1024 + kvh * HD;
    const short* vbase = QKV + (size_t)b * T_SEQ * QKVW + 1280 + kvh * HD;

    short8_t ones;
    #pragma unroll
    for (int i = 0; i < 8; ++i) ones[i] = (short)0x3F80;

    float mrow[4], lrow[4];
    f32x4 oacc[4];
    #pragma unroll
    for (int r = 0; r < 4; ++r) { mrow[r] = -INFINITY; lrow[r] = 0.f; }
    #pragma unroll
    for (int dt = 0; dt < 4; ++dt) oacc[dt] = (f32x4){0.f, 0.f, 0.f, 0.f};

    const int kkey = tid >> 3, kd = (tid & 7) * 8;
    const int vkey = tid & 63, vd = (tid >> 6) * 8;

    short8_t kr[2], vr[2];
    #pragma unroll
    for (int it = 0; it < 2; ++it) {
        kr[it] = *(const short8_t*)(kbase + (size_t)(kkey + 32 * it) * QKVW + kd);
        vr[it] = *(const short8_t*)(vbase + (size_t)vkey * QKVW + vd + 32 * it);
    }

    for (int c = 0; c <= ct; ++c) {
        __syncthreads();
        #pragma unroll
        for (int it = 0; it < 2; ++it) {
            *(short8_t*)&sK[kkey + 32 * it][kd] = kr[it];
            #pragma unroll
            for (int i = 0; i < 8; ++i) sVt[vd + 32 * it + i][vkey] = vr[it][i];
        }
        __syncthreads();
        if (c < ct) {
            int jn = (c + 1) * 64;
            #pragma unroll
            for (int it = 0; it < 2; ++it) {
                kr[it] = *(const short8_t*)(kbase + (size_t)(jn + kkey + 32 * it) * QKVW + kd);
                vr[it] = *(const short8_t*)(vbase + (size_t)(jn + vkey) * QKVW + vd + 32 * it);
            }
        }

        // S = Q K^T (log2-domain, pre-scaled)
        f32x4 sacc[4];
        #pragma unroll
        for (int nt = 0; nt < 4; ++nt) {
            f32x4 z = {0.f, 0.f, 0.f, 0.f};
            short8_t kf0 = *(const short8_t*)&sK[l16 + 16 * nt][quad * 8];
            short8_t kf1 = *(const short8_t*)&sK[l16 + 16 * nt][quad * 8 + 32];
            z = __builtin_amdgcn_mfma_f32_16x16x32_bf16(qf0, kf0, z, 0, 0, 0);
            z = __builtin_amdgcn_mfma_f32_16x16x32_bf16(qf1, kf1, z, 0, 0, 0);
            sacc[nt] = z;
        }

        bool maskc = (c == ct);
        int j0 = c * 64;
        float al[4];
        #pragma unroll
        for (int r = 0; r < 4; ++r) {
            int trow = tq * 16 + quad * 4 + r;
            float sv[4], vmax = -INFINITY;
            #pragma unroll
            for (int nt = 0; nt < 4; ++nt) {
                float s = sacc[nt][r];
                if (maskc && (j0 + 16 * nt + l16 > trow)) s = -INFINITY;
                sv[nt] = s;
                vmax = fmaxf(vmax, s);
            }
            vmax = dpp_max16(vmax);
            float mnew = fmaxf(mrow[r], vmax);
            al[r] = exp2f(mrow[r] - mnew);
            mrow[r] = mnew;
            #pragma unroll
            for (int nt = 0; nt < 4; ++nt)
                sP[w][quad * 4 + r][16 * nt + l16] = f2bs_trunc(exp2f(sv[nt] - mnew));
        }
        if (__any((al[0] < 1.f) || (al[1] < 1.f) || (al[2] < 1.f) || (al[3] < 1.f))) {
            #pragma unroll
            for (int r = 0; r < 4; ++r) lrow[r] *= al[r];
            #pragma unroll
            for (int dt = 0; dt < 4; ++dt) {
                f32x4 o = oacc[dt];
                o[0] *= al[0]; o[1] *= al[1]; o[2] *= al[2]; o[3] *= al[3];
                oacc[dt] = o;
            }
        }

        short8_t pf0 = *(const short8_t*)&sP[w][l16][quad * 8];
        short8_t pf1 = *(const short8_t*)&sP[w][l16][quad * 8 + 32];
        f32x4 rs = {0.f, 0.f, 0.f, 0.f};
        rs = __builtin_amdgcn_mfma_f32_16x16x32_bf16(pf0, ones, rs, 0, 0, 0);
        rs = __builtin_amdgcn_mfma_f32_16x16x32_bf16(pf1, ones, rs, 0, 0, 0);
        #pragma unroll
        for (int r = 0; r < 4; ++r) lrow[r] += rs[r];
        #pragma unroll
        for (int dt = 0; dt < 4; ++dt) {
            short8_t vf0 = *(const short8_t*)&sVt[l16 + 16 * dt][quad * 8];
            short8_t vf1 = *(const short8_t*)&sVt[l16 + 16 * dt][quad * 8 + 32];
            oacc[dt] = __builtin_amdgcn_mfma_f32_16x16x32_bf16(pf0, vf0, oacc[dt], 0, 0, 0);
            oacc[dt] = __builtin_amdgcn_mfma_f32_16x16x32_bf16(pf1, vf1, oacc[dt], 0, 0, 0);
        }
    }

    #pragma unroll
    for (int r = 0; r < 4; ++r) {
        int m = quad * 4 + r;
        float inv = __builtin_amdgcn_rcpf(lrow[r]);
        #pragma unroll
        for (int dt = 0; dt < 4; ++dt)
            O[((size_t)b * T_SEQ + tq * 16 + m) * C_DIM + h * HD + 16 * dt + l16] =
                f2bs(oacc[dt][r] * inv);
    }
}

// ---------------------------------------------------------------------------
extern "C" void kernel_launch(void* const* d_in, const int* in_sizes, int n_in,
                              void* d_out, int out_size, void* d_ws, size_t ws_size,
                              hipStream_t stream)
{
    const float* x   = (const float*)d_in[0];
    const float* w_q = (const float*)d_in[1];
    const float* b_q = (const float*)d_in[2];
    const float* w_k = (const float*)d_in[3];
    const float* b_k = (const float*)d_in[4];
    const float* w_v = (const float*)d_in[5];
    const float* b_v = (const float*)d_in[6];
    const float* w_o = (const float*)d_in[7];
    const float* b_o = (const float*)d_in[8];
    float* out = (float*)d_out;

    char* ws = (char*)d_ws;
    short*  Xb   = (short*) (ws);                              // 8 MB
    short*  Ab   = (short*) (ws + ((size_t)8  << 20));         // 8 MB
    short*  QKVb = (short*) (ws + ((size_t)16 << 20));         // 12 MB
    short*  Wqkv = (short*) (ws + ((size_t)28 << 20));         // 3 MB
    short*  Wto  = (short*) (ws + ((size_t)31 << 20));         // 2 MB
    float*  Bqkv = (float*) (ws + ((size_t)33 << 20));         // 6 KB
    float2* Tab  = (float2*)(ws + ((size_t)33 << 20) + 8192);  // 512 KB

    const int M = B_SZ * T_SEQ;   // 4096

    prep_kernel<<<6918, 256, 0, stream>>>(
        x, w_q, w_k, w_v, w_o, b_q, b_k, b_v, Xb, Wqkv, Wto, Bqkv, Tab);

    gemm_mfma_bt<short><<<dim3(QKVW / 128, M / 128), 256, 0, stream>>>(
        Xb, Wqkv, Bqkv, QKVb, M, QKVW, C_DIM);

    rope_k_kernel<<<2048, 256, 0, stream>>>(QKVb, Tab);

    attn_mfma5<<<B_SZ * NKV * 128, 256, 0, stream>>>(QKVb, Tab, Ab);

    gemm_mfma_bt<float><<<dim3(C_DIM / 128, M / 128), 256, 0, stream>>>(
        Ab, Wto, b_o, out, M, C_DIM, C_DIM);
}

// Round 10
// 181.510 us; speedup vs baseline: 14.9256x; 1.0482x over previous
//
#include <hip/hip_runtime.h>
#include <hip/hip_bf16.h>

typedef __hip_bfloat16 bf16;
typedef __attribute__((ext_vector_type(8))) short short8_t;
typedef __attribute__((ext_vector_type(4))) short short4_t;
typedef __attribute__((ext_vector_type(4))) float f32x4;

#define B_SZ   2
#define T_SEQ  2048
#define C_DIM  1024
#define NH     16
#define NKV    4
#define HD     64
#define QKVW   1536          // fused QKV row width (1024 Q | 256 K | 256 V)

#define LOG2_BASE_OVER_32 0.4152410118609203f
#define Q_SCALE 0.1803368801111204f   // 0.125 * log2(e)

__device__ __forceinline__ short f2bs(float f) {
    unsigned u = __float_as_uint(f);
    u += 0x7FFFu + ((u >> 16) & 1u);
    return (short)(u >> 16);
}
__device__ __forceinline__ short f2bs_trunc(float f) {
    return (short)(__float_as_uint(f) >> 16);
}
__device__ __forceinline__ float bs2f(short s) {
    unsigned u = ((unsigned)(unsigned short)s) << 16;
    return __uint_as_float(u);
}

__device__ __forceinline__ void store_c(float* p, float v) { *p = v; }
__device__ __forceinline__ void store_c(short* p, float v) { *p = f2bs(v); }

// ---------------------------------------------------------------------------
// Fused prep (round-9 version: x->bf16, transposes, bias concat, RoPE table)
// ---------------------------------------------------------------------------
__device__ __forceinline__ void transpose_tile(
    const float* __restrict__ W, short* __restrict__ Wt,
    int K, int N, int n0, int k0, int tid)
{
    __shared__ float tile[32][33];
    int tx = tid & 31, ty = tid >> 5;
    #pragma unroll
    for (int i = 0; i < 4; ++i)
        tile[ty + 8 * i][tx] = W[(size_t)(k0 + ty + 8 * i) * N + n0 + tx];
    __syncthreads();
    #pragma unroll
    for (int i = 0; i < 4; ++i)
        Wt[(size_t)(n0 + ty + 8 * i) * K + k0 + tx] = f2bs(tile[tx][ty + 8 * i]);
}

__global__ __launch_bounds__(256) void prep_kernel(
    const float* __restrict__ x,
    const float* __restrict__ w_q, const float* __restrict__ w_k,
    const float* __restrict__ w_v, const float* __restrict__ w_o,
    const float* __restrict__ b_q, const float* __restrict__ b_k,
    const float* __restrict__ b_v,
    short* __restrict__ Xb, short* __restrict__ Wqkv, short* __restrict__ Wto,
    float* __restrict__ Bqkv, float2* __restrict__ Tab)
{
    int blk = blockIdx.x, tid = threadIdx.x;
    if (blk < 4096) {
        int i = blk * 1024 + tid * 4;
        float4 v = *(const float4*)(x + i);
        short4_t o;
        o[0] = f2bs(v.x); o[1] = f2bs(v.y); o[2] = f2bs(v.z); o[3] = f2bs(v.w);
        *(short4_t*)(Xb + i) = o;
    } else if (blk < 5120) {
        int l = blk - 4096;
        transpose_tile(w_q, Wqkv, C_DIM, C_DIM, (l & 31) * 32, (l >> 5) * 32, tid);
    } else if (blk < 5376) {
        int l = blk - 5120;
        transpose_tile(w_k, Wqkv + (size_t)1024 * C_DIM, C_DIM, 256,
                       (l & 7) * 32, (l >> 3) * 32, tid);
    } else if (blk < 5632) {
        int l = blk - 5376;
        transpose_tile(w_v, Wqkv + (size_t)1280 * C_DIM, C_DIM, 256,
                       (l & 7) * 32, (l >> 3) * 32, tid);
    } else if (blk < 6656) {
        int l = blk - 5632;
        transpose_tile(w_o, Wto, C_DIM, C_DIM, (l & 31) * 32, (l >> 5) * 32, tid);
    } else if (blk < 6662) {
        int i = (blk - 6656) * 256 + tid;
        float v;
        if (i < 1024)      v = b_q[i];
        else if (i < 1280) v = b_k[i - 1024];
        else               v = b_v[i - 1280];
        Bqkv[i] = v;
    } else {
        int idx = (blk - 6662) * 256 + tid;
        int t = idx >> 5, i = idx & 31;
        float ang = (float)t * exp2f(-(float)i * LOG2_BASE_OVER_32);
        Tab[idx] = make_float2(cosf(ang), sinf(ang));
    }
}

// ---------------------------------------------------------------------------
// MFMA GEMM (B^T input), double-buffered LDS (round-8 version, unchanged)
// ---------------------------------------------------------------------------
template <typename CT>
__global__ __launch_bounds__(256) void gemm_mfma_bt(
    const short* __restrict__ A, const short* __restrict__ Bt,
    const float* __restrict__ bias, CT* __restrict__ C,
    int M, int N, int K)
{
    __shared__ __align__(16) short sA[2][128][40];
    __shared__ __align__(16) short sB[2][128][40];

    int m0 = blockIdx.y * 128;
    int n0 = blockIdx.x * 128;
    int tid  = threadIdx.x;
    int w    = tid >> 6, lane = tid & 63;
    int quad = lane >> 4, l16 = lane & 15;
    int wm = w & 1, wn = w >> 1;

    f32x4 acc[4][4] = {};

    short8_t ra[2], rb[2];
    #pragma unroll
    for (int it = 0; it < 2; ++it) {
        int slot = tid + 256 * it, row = slot >> 2, g = (slot & 3) * 8;
        ra[it] = *(const short8_t*)(A  + (size_t)(m0 + row) * K + g);
        rb[it] = *(const short8_t*)(Bt + (size_t)(n0 + row) * K + g);
    }

    int buf = 0;
    for (int k0 = 0; k0 < K; k0 += 32, buf ^= 1) {
        #pragma unroll
        for (int it = 0; it < 2; ++it) {
            int slot = tid + 256 * it, row = slot >> 2, g = (slot & 3) * 8;
            *(short8_t*)&sA[buf][row][g] = ra[it];
            *(short8_t*)&sB[buf][row][g] = rb[it];
        }
        if (k0 + 32 < K) {
            #pragma unroll
            for (int it = 0; it < 2; ++it) {
                int slot = tid + 256 * it, row = slot >> 2, g = (slot & 3) * 8;
                ra[it] = *(const short8_t*)(A  + (size_t)(m0 + row) * K + k0 + 32 + g);
                rb[it] = *(const short8_t*)(Bt + (size_t)(n0 + row) * K + k0 + 32 + g);
            }
        }
        __syncthreads();

        short8_t af[4], bfr[4];
        #pragma unroll
        for (int mt = 0; mt < 4; ++mt)
            af[mt] = *(const short8_t*)&sA[buf][wm * 64 + mt * 16 + l16][quad * 8];
        #pragma unroll
        for (int nt = 0; nt < 4; ++nt)
            bfr[nt] = *(const short8_t*)&sB[buf][wn * 64 + nt * 16 + l16][quad * 8];
        #pragma unroll
        for (int mt = 0; mt < 4; ++mt)
            #pragma unroll
            for (int nt = 0; nt < 4; ++nt)
                acc[mt][nt] = __builtin_amdgcn_mfma_f32_16x16x32_bf16(
                    af[mt], bfr[nt], acc[mt][nt], 0, 0, 0);
    }

    #pragma unroll
    for (int mt = 0; mt < 4; ++mt) {
        #pragma unroll
        for (int nt = 0; nt < 4; ++nt) {
            int col = n0 + wn * 64 + nt * 16 + l16;
            float bv = bias[col];
            #pragma unroll
            for (int r = 0; r < 4; ++r) {
                int row = m0 + wm * 64 + mt * 16 + quad * 4 + r;
                store_c(&C[(size_t)row * N + col], acc[mt][nt][r] + bv);
            }
        }
    }
}

// ---------------------------------------------------------------------------
// RoPE on K (table) + V transpose into Vt[256][4096] (Vt[d][b*T+t]).
//   blocks [0,2048): rope K pairs; [2048,2304): 64x64 V transpose tiles.
// ---------------------------------------------------------------------------
__global__ __launch_bounds__(256) void rope_k_transpose_v(
    short* __restrict__ QKV, const float2* __restrict__ Tab,
    short* __restrict__ Vt)
{
    int blk = blockIdx.x, tid = threadIdx.x;
    if (blk < 2048) {
        int g = blk * 256 + tid;
        int row = g >> 7, pi = g & 127;
        int col = 1024 + pi * 2;
        int t = row & (T_SEQ - 1);
        int i = pi & 31;
        size_t base = (size_t)row * QKVW + col;
        float e = bs2f(QKV[base]);
        float o = bs2f(QKV[base + 1]);
        float2 cs = Tab[t * 32 + i];
        QKV[base]     = f2bs(e * cs.x - o * cs.y);
        QKV[base + 1] = f2bs(e * cs.y + o * cs.x);
    } else {
        __shared__ __align__(16) short sT[64][72];
        int l = blk - 2048;              // 256 tiles: 4 dim-tiles x 64 row-tiles
        int d0 = (l >> 6) * 64;
        int r0 = (l & 63) * 64;
        int i0 = tid >> 3, seg = (tid & 7) * 8;
        #pragma unroll
        for (int it = 0; it < 2; ++it) {
            int i = i0 + 32 * it;
            *(short8_t*)&sT[i][seg] =
                *(const short8_t*)(QKV + (size_t)(r0 + i) * QKVW + 1280 + d0 + seg);
        }
        __syncthreads();
        #pragma unroll
        for (int it = 0; it < 2; ++it) {
            int d = i0 + 32 * it;
            short8_t o;
            #pragma unroll
            for (int k = 0; k < 8; ++k) o[k] = sT[seg + k][d];
            *(short8_t*)(Vt + (size_t)(d0 + d) * (B_SZ * T_SEQ) + r0 + seg) = o;
        }
    }
}

// ---------------------------------------------------------------------------
// MFMA flash attention v6 — S^T formulation.
//   QK^T computed transposed (A=K-frag, B=Q-frag -> same per-lane data as
//   before, zero extra cost). Softmax state per-lane (q = l16): reg max/sum
//   + shfl_xor(16/32). Each lane holds 4 contiguous keys per tile -> P
//   written transposed with 4 ds_write_b64 (conflict-free), read back as
//   b128 A-frag. V staged from pre-transposed Vt with b128 writes.
// ---------------------------------------------------------------------------
__global__ __launch_bounds__(256) void attn_mfma6(
    const short* __restrict__ QKV, const short* __restrict__ Vt,
    const float2* __restrict__ Tab, short* __restrict__ O)
{
    __shared__ __align__(16) short sK [64][72];
    __shared__ __align__(16) short sVt[64][72];
    __shared__ __align__(16) short sP [4][16][72];

    const int tid  = threadIdx.x;
    const int w    = tid >> 6;
    const int lane = tid & 63;
    const int quad = lane >> 4;
    const int l16  = lane & 15;

    int blk = blockIdx.x;
    int grp = blk & 7;                 // (b,kvh)
    int tq  = 127 - (blk >> 3);        // long tiles first
    int kvh = grp & 3;
    int b   = grp >> 2;
    int h   = kvh * 4 + w;
    int ct  = tq >> 2;

    // ---- Q frags: load, rope via table, scale by Q_SCALE (B-frag layout)
    const short* qptr = QKV + ((size_t)(b * T_SEQ + tq * 16 + l16)) * QKVW + h * HD;
    short8_t q0r = *(const short8_t*)(qptr + quad * 8);
    short8_t q1r = *(const short8_t*)(qptr + quad * 8 + 32);
    int tg = tq * 16 + l16;
    const float2* tb = Tab + tg * 32 + quad * 4;
    short8_t qf0, qf1;
    #pragma unroll
    for (int j = 0; j < 4; ++j) {
        float2 cs0 = tb[j];
        float e0 = bs2f(q0r[2 * j]), o0 = bs2f(q0r[2 * j + 1]);
        qf0[2 * j]     = f2bs((e0 * cs0.x - o0 * cs0.y) * Q_SCALE);
        qf0[2 * j + 1] = f2bs((e0 * cs0.y + o0 * cs0.x) * Q_SCALE);
        float2 cs1 = tb[j + 16];
        float e1 = bs2f(q1r[2 * j]), o1 = bs2f(q1r[2 * j + 1]);
        qf1[2 * j]     = f2bs((e1 * cs1.x - o1 * cs1.y) * Q_SCALE);
        qf1[2 * j + 1] = f2bs((e1 * cs1.y + o1 * cs1.x) * Q_SCALE);
    }

    const short* kbase  = QKV + (size_t)b * T_SEQ * QKVW + 1024 + kvh * HD;
    const short* vtbase = Vt + (size_t)(kvh * HD) * (B_SZ * T_SEQ) + b * T_SEQ;

    // per-lane softmax state for q = tq*16 + l16 (replicated across quads)
    float m_l = -INFINITY, l_l = 0.f;
    f32x4 oacc[4];                      // O[q=quad*4+r][d=16dt+l16]
    #pragma unroll
    for (int dt = 0; dt < 4; ++dt) oacc[dt] = (f32x4){0.f, 0.f, 0.f, 0.f};

    const int kkey = tid >> 3, kd = (tid & 7) * 8;    // K: 8 lanes/key
    const int vdim = tid >> 3, vseg = (tid & 7) * 8;  // V^T: 8 lanes/dim

    short8_t kr[2], vr[2];
    #pragma unroll
    for (int it = 0; it < 2; ++it) {
        kr[it] = *(const short8_t*)(kbase + (size_t)(kkey + 32 * it) * QKVW + kd);
        vr[it] = *(const short8_t*)(vtbase + (size_t)(vdim + 32 * it) * (B_SZ * T_SEQ) + vseg);
    }

    for (int c = 0; c <= ct; ++c) {
        __syncthreads();
        #pragma unroll
        for (int it = 0; it < 2; ++it) {
            *(short8_t*)&sK [kkey + 32 * it][kd]   = kr[it];
            *(short8_t*)&sVt[vdim + 32 * it][vseg] = vr[it];
        }
        __syncthreads();
        if (c < ct) {
            int jn = (c + 1) * 64;
            #pragma unroll
            for (int it = 0; it < 2; ++it) {
                kr[it] = *(const short8_t*)(kbase + (size_t)(jn + kkey + 32 * it) * QKVW + kd);
                vr[it] = *(const short8_t*)(vtbase + (size_t)(vdim + 32 * it) * (B_SZ * T_SEQ) + jn + vseg);
            }
        }

        // S^T = K Q^T : sacc[kt] rows = keys 16kt+quad*4+r, col = q = l16
        f32x4 sacc[4];
        #pragma unroll
        for (int kt = 0; kt < 4; ++kt) {
            f32x4 z = {0.f, 0.f, 0.f, 0.f};
            short8_t kf0 = *(const short8_t*)&sK[l16 + 16 * kt][quad * 8];
            short8_t kf1 = *(const short8_t*)&sK[l16 + 16 * kt][quad * 8 + 32];
            z = __builtin_amdgcn_mfma_f32_16x16x32_bf16(kf0, qf0, z, 0, 0, 0);
            z = __builtin_amdgcn_mfma_f32_16x16x32_bf16(kf1, qf1, z, 0, 0, 0);
            sacc[kt] = z;
        }

        // causal mask (last chunk only): key j0+16kt+quad*4+r > q
        if (c == ct) {
            int j0 = c * 64;
            #pragma unroll
            for (int kt = 0; kt < 4; ++kt)
                #pragma unroll
                for (int r = 0; r < 4; ++r)
                    if (j0 + 16 * kt + quad * 4 + r > tg) sacc[kt][r] = -INFINITY;
        }

        // per-lane max over 16 regs, then cross-quad
        float vmax = sacc[0][0];
        #pragma unroll
        for (int kt = 0; kt < 4; ++kt)
            #pragma unroll
            for (int r = 0; r < 4; ++r) vmax = fmaxf(vmax, sacc[kt][r]);
        vmax = fmaxf(vmax, __shfl_xor(vmax, 16));
        vmax = fmaxf(vmax, __shfl_xor(vmax, 32));
        float mnew = fmaxf(m_l, vmax);
        float al = exp2f(m_l - mnew);
        m_l = mnew;

        // P^T = exp2(S^T - m); write transposed (4x ds_write_b64) + row sum
        float psum = 0.f;
        #pragma unroll
        for (int kt = 0; kt < 4; ++kt) {
            short4_t pk;
            #pragma unroll
            for (int r = 0; r < 4; ++r) {
                float p = exp2f(sacc[kt][r] - mnew);
                psum += p;
                pk[r] = f2bs_trunc(p);
            }
            *(short4_t*)&sP[w][l16][16 * kt + 4 * quad] = pk;
        }
        psum += __shfl_xor(psum, 16);
        psum += __shfl_xor(psum, 32);
        l_l = l_l * al + psum;

        // rescale O (row-space alpha via bpermute), skip when maxes unchanged
        if (__any(al < 1.f)) {
            #pragma unroll
            for (int r = 0; r < 4; ++r) {
                float alr = __shfl(al, quad * 4 + r);
                #pragma unroll
                for (int dt = 0; dt < 4; ++dt) oacc[dt][r] *= alr;
            }
        }

        // PV: A = P (A-layout from sP), B = V (from sVt rows)
        short8_t pf0 = *(const short8_t*)&sP[w][l16][quad * 8];
        short8_t pf1 = *(const short8_t*)&sP[w][l16][quad * 8 + 32];
        #pragma unroll
        for (int dt = 0; dt < 4; ++dt) {
            short8_t vf0 = *(const short8_t*)&sVt[16 * dt + l16][quad * 8];
            short8_t vf1 = *(const short8_t*)&sVt[16 * dt + l16][quad * 8 + 32];
            oacc[dt] = __builtin_amdgcn_mfma_f32_16x16x32_bf16(pf0, vf0, oacc[dt], 0, 0, 0);
            oacc[dt] = __builtin_amdgcn_mfma_f32_16x16x32_bf16(pf1, vf1, oacc[dt], 0, 0, 0);
        }
    }

    // epilogue: O[b, tq*16+q][h*64+d] = oacc / l
    #pragma unroll
    for (int r = 0; r < 4; ++r) {
        int m = quad * 4 + r;
        float lr = __shfl(l_l, quad * 4 + r);
        float inv = __builtin_amdgcn_rcpf(lr);
        #pragma unroll
        for (int dt = 0; dt < 4; ++dt)
            O[((size_t)b * T_SEQ + tq * 16 + m) * C_DIM + h * HD + 16 * dt + l16] =
                f2bs(oacc[dt][r] * inv);
    }
}

// ---------------------------------------------------------------------------
extern "C" void kernel_launch(void* const* d_in, const int* in_sizes, int n_in,
                              void* d_out, int out_size, void* d_ws, size_t ws_size,
                              hipStream_t stream)
{
    const float* x   = (const float*)d_in[0];
    const float* w_q = (const float*)d_in[1];
    const float* b_q = (const float*)d_in[2];
    const float* w_k = (const float*)d_in[3];
    const float* b_k = (const float*)d_in[4];
    const float* w_v = (const float*)d_in[5];
    const float* b_v = (const float*)d_in[6];
    const float* w_o = (const float*)d_in[7];
    const float* b_o = (const float*)d_in[8];
    float* out = (float*)d_out;

    char* ws = (char*)d_ws;
    short*  Xb   = (short*) (ws);                              // 8 MB
    short*  Ab   = (short*) (ws + ((size_t)8  << 20));         // 8 MB
    short*  QKVb = (short*) (ws + ((size_t)16 << 20));         // 12 MB
    short*  Wqkv = (short*) (ws + ((size_t)28 << 20));         // 3 MB
    short*  Wto  = (short*) (ws + ((size_t)31 << 20));         // 2 MB
    float*  Bqkv = (float*) (ws + ((size_t)33 << 20));         // 6 KB
    float2* Tab  = (float2*)(ws + ((size_t)33 << 20) + 8192);  // 512 KB
    short*  Vt   = (short*) (ws + ((size_t)34 << 20));         // 2 MB

    const int M = B_SZ * T_SEQ;   // 4096

    prep_kernel<<<6918, 256, 0, stream>>>(
        x, w_q, w_k, w_v, w_o, b_q, b_k, b_v, Xb, Wqkv, Wto, Bqkv, Tab);

    gemm_mfma_bt<short><<<dim3(QKVW / 128, M / 128), 256, 0, stream>>>(
        Xb, Wqkv, Bqkv, QKVb, M, QKVW, C_DIM);

    rope_k_transpose_v<<<2304, 256, 0, stream>>>(QKVb, Tab, Vt);

    attn_mfma6<<<B_SZ * NKV * 128, 256, 0, stream>>>(QKVb, Vt, Tab, Ab);

    gemm_mfma_bt<float><<<dim3(C_DIM / 128, M / 128), 256, 0, stream>>>(
        Ab, Wto, b_o, out, M, C_DIM, C_DIM);
}